// Round 2
// baseline (683.409 us; speedup 1.0000x reference)
//
#include <hip/hip_runtime.h>
#include <hip/hip_bf16.h>

// Round 14: fix r13's zq mismatch. r13: only output 2 (zq_p) failed at
// absmax 1.9e-3 = max code diff -> a handful of argmin flips. Root cause:
// np's reference distances d = RN(RN(zn-2dot)+cn) carry ~5e-8 rounding
// noise at the zn scale; ~75 vectors have true gaps below that, and their
// np-argmin is decided by f32 rounding order. r12 passed by replicating
// np's formula bit-exactly. r13's fallback dropped zn from the rounding
// path (true-ranking, not np-ranking) and the cert bound didn't cover np's
// own noise. Fix: (1) fallback computes d = (zn - 2*dot) + cn with
// ascending sequential fmaf for dot AND zn (r12-proven bit-match to np's
// BLAS), first-min lexicographic tie-break; loss uses bd directly (it now
// includes zn). (2) cert eb = 3e-4*sqrt(zn)*cmax + 2e-6*zn: first term
// covers our bf16-split MFMA error (25x margin), second covers np's
// rounding (5x margin) so certified vectors agree with np too. MFMA
// distance path (3x mfma_f32_16x16x32_bf16 hi/lo split, cn as C-init, B
// streamed from L2, no LDS) unchanged from r13. All other kernels
// unchanged from r12.
// Outputs (f32): out[1048576] | loss[1] | zq_p[4194304].

typedef float f32x4  __attribute__((ext_vector_type(4)));
typedef short bf16x8 __attribute__((ext_vector_type(8)));

__device__ __forceinline__ float silu_rw(float x){ return x / (1.f + expf(-x)); }
__device__ __forceinline__ float b2f_rw(__hip_bfloat16 v){ return __bfloat162float(v); }
__device__ __forceinline__ float ldv_rw(const void* p, int i, int f32m){
  if (f32m) return ((const float*)p)[i];
  return b2f_rw(((const __hip_bfloat16*)p)[i]);
}
__device__ __forceinline__ unsigned short f2bf_rw(float x){   // f32 -> bf16 RNE
  unsigned u = __float_as_uint(x);
  unsigned r = ((u >> 16) & 1u) + 0x7FFFu;
  return (unsigned short)((u + r) >> 16);
}
__device__ __forceinline__ float bf2f_rw(unsigned short h){
  return __uint_as_float(((unsigned)h) << 16);
}

// ---------------- workspace layout (float offsets) ----------------
#define FLAGS_OFF 0
#define LOSS_OFF  4
#define STATS_OFF 8
#define CNT_OFF   72         // 8 ints: fallback counters per chunk (4 phylo + 4 non)
#define CMAX_OFF  80         // max_j |c_j| (f32)
#define CB32_OFF  128        // 1024x32 f32
#define CBN_OFF   32896      // 1024
#define IDXP_OFF  33984      // 131072 int
#define IDXN_OFF  165056     // 131072 int
#define CBH_OFF   296192     // 1024x32 bf16 hi  (16384 f32 slots)
#define CBL_OFF   312576     // 1024x32 bf16 lo
#define LIST_OFF  328960     // 131072 int (uncertain list, reused per chunk)
#define R2_OFF    460032     // lnp -> hcat_p accum (524288)
#define R3_OFF    984320     // lnn -> hcat_n accum (524288)
#define R1_OFF    1508608    // h (1048576) / z chunks (CS*262144)

// ---------------- input dtype probe + zero accumulators ----------------
__global__ __launch_bounds__(256) void detect_rw(const void* cbv, float* wsb){
  __shared__ int bad;
  if (threadIdx.x == 0) bad = 0;
  __syncthreads();
  const unsigned short* u = (const unsigned short*)cbv;
  int local = 0;
  for (int i = threadIdx.x; i < 32768; i += 256){
    unsigned e = (u[i] >> 7) & 0xFF;
    if (e >= 126) local = 1;
  }
  if (local) bad = 1;
  __syncthreads();
  if (threadIdx.x == 0){
    wsb[FLAGS_OFF] = bad ? 1.f : 0.f;   // 1.0 => inputs are f32
    wsb[LOSS_OFF] = 0.f; wsb[LOSS_OFF + 1] = 0.f;
    int* c = (int*)(wsb + CNT_OFF);
    #pragma unroll
    for (int k = 0; k < 8; ++k) c[k] = 0;
    wsb[CMAX_OFF] = 0.f;
  }
}

// ---------------- codebook -> f32 + |c|^2 + bf16 hi/lo split ----------------
__global__ __launch_bounds__(256) void cbprep_rw(const void* cbv, const float* flags,
                                                 float* cb32, float* cbn,
                                                 short* cbh, short* cbl, float* cmaxp){
  const int f32m = (flags[0] != 0.f);
  int j = blockIdx.x * 256 + threadIdx.x;
  if (j < 1024){
    float s = 0.f;
    for (int e = 0; e < 32; ++e){
      float v = ldv_rw(cbv, j*32 + e, f32m);
      cb32[j*32 + e] = v;
      unsigned short h = f2bf_rw(v);
      cbh[j*32 + e] = (short)h;
      cbl[j*32 + e] = (short)f2bf_rw(v - bf2f_rw(h));
      s += v*v;
    }
    cbn[j] = s;
    atomicMax((int*)cmaxp, __float_as_int(sqrtf(s)));  // positive floats: int-bit monotone
  }
}

// ---------------- gemm2 (r11, verified): 32px x 64out tiles ----------------
template<int KCH, int INMODE, bool OUTSILU, bool ATOMIC, int LEVELS>
__global__ __launch_bounds__(256) void gemm2_rw(
    const float* __restrict__ inF, const float* __restrict__ inF2,
    const void* __restrict__ inV,
    const void* __restrict__ W, const void* __restrict__ biasO,
    const void* __restrict__ sbA, const void* __restrict__ sbB,
    const int* __restrict__ idxin, const float* __restrict__ cb32,
    float* __restrict__ outF, const float* __restrict__ flags,
    int KDIM, int OUTC, int o_off, int b_base, int ib_sub, int ob_sub)
{
  __shared__ float As[32][32];
  __shared__ float Bs[32][68];
  __shared__ int   IdxS[32][32];

  const int f32m = (flags[0] != 0.f);
  const int t  = threadIdx.x;
  const int q0 = (blockIdx.x << 5) + (b_base << 8);
  const int b  = q0 >> 8;
  const int p0 = q0 & 255;
  const int o0 = blockIdx.y << 6;
  const int k0base = blockIdx.z * KCH;
  const int tx = t & 15, ty = t >> 4;
  float acc[4][2] = {};

  const int sch = t >> 3, spx = (t & 7) << 2;

  if constexpr (INMODE == 3){
    #pragma unroll
    for (int j = 0; j < 4; ++j){
      const int p = p0 + spx + j;
      if constexpr (LEVELS == 4){
        const int l = sch >> 3, kp = sch & 7;
        IdxS[sch][spx + j] = idxin[b*8192 + (((kp << 8) + p) << 2) + l];
      } else {
        IdxS[sch][spx + j] = idxin[b*8192 + (sch << 8) + p];
      }
    }
    __syncthreads();
  }

  for (int kc = 0; kc < KCH; kc += 32){
    const int k0 = k0base + kc;
    if constexpr (INMODE == 0){
      const float4 v = *reinterpret_cast<const float4*>(
          &inF[(((b - ib_sub)*KDIM + k0 + sch) << 8) + p0 + spx]);
      *reinterpret_cast<float4*>(&As[sch][spx]) = v;
    } else if constexpr (INMODE == 2){
      if (f32m){
        const float* xf = (const float*)inV;
        float4 v = *reinterpret_cast<const float4*>(&xf[((b*KDIM + k0 + sch) << 8) + p0 + spx]);
        v.x = silu_rw(v.x); v.y = silu_rw(v.y); v.z = silu_rw(v.z); v.w = silu_rw(v.w);
        *reinterpret_cast<float4*>(&As[sch][spx]) = v;
      } else {
        const __hip_bfloat16* xb = (const __hip_bfloat16*)inV;
        const int off = ((b*KDIM + k0 + sch) << 8) + p0 + spx;
        #pragma unroll
        for (int j = 0; j < 4; ++j) As[sch][spx + j] = silu_rw(b2f_rw(xb[off + j]));
      }
    } else if constexpr (INMODE == 3){
      const int e = k0 >> 5;
      #pragma unroll
      for (int j = 0; j < 4; ++j)
        As[sch][spx + j] = cb32[((IdxS[sch][spx + j] & 1023) << 5) + e];
    } else { // INMODE 5
      const float* src = (k0 < 128) ? inF : inF2;
      const void* sb   = (k0 < 128) ? sbA : sbB;
      const int kh = k0 & 127;
      const float bb = ldv_rw(sb, kh + sch, f32m);
      float4 v = *reinterpret_cast<const float4*>(&src[((b*128 + kh + sch) << 8) + p0 + spx]);
      v.x = silu_rw(v.x + bb); v.y = silu_rw(v.y + bb);
      v.z = silu_rw(v.z + bb); v.w = silu_rw(v.w + bb);
      *reinterpret_cast<float4*>(&As[sch][spx]) = v;
    }
    if (f32m){
      const float* Wf = (const float*)W;
      #pragma unroll
      for (int r = 0; r < 8; ++r){
        int ii = t + (r << 8); int oo = ii >> 5, cc = ii & 31;
        Bs[cc][oo] = Wf[(o0 + oo)*KDIM + k0 + cc];
      }
    } else {
      const __hip_bfloat16* Wb = (const __hip_bfloat16*)W;
      #pragma unroll
      for (int r = 0; r < 8; ++r){
        int ii = t + (r << 8); int oo = ii >> 5, cc = ii & 31;
        Bs[cc][oo] = b2f_rw(Wb[(o0 + oo)*KDIM + k0 + cc]);
      }
    }
    __syncthreads();
    #pragma unroll
    for (int kk = 0; kk < 32; ++kk){
      const float2 a = *reinterpret_cast<const float2*>(&As[kk][tx << 1]);
      const float4 w = *reinterpret_cast<const float4*>(&Bs[kk][ty << 2]);
      acc[0][0] += w.x*a.x; acc[0][1] += w.x*a.y;
      acc[1][0] += w.y*a.x; acc[1][1] += w.y*a.y;
      acc[2][0] += w.z*a.x; acc[2][1] += w.z*a.y;
      acc[3][0] += w.w*a.x; acc[3][1] += w.w*a.y;
    }
    __syncthreads();
  }
  #pragma unroll
  for (int i = 0; i < 4; ++i){
    const int o = o0 + (ty << 2) + i;
    const int base = (((b - ob_sub)*OUTC + o_off + o) << 8) + p0 + (tx << 1);
    if constexpr (ATOMIC){
      atomicAdd(&outF[base + 0], acc[i][0]);
      atomicAdd(&outF[base + 1], acc[i][1]);
    } else {
      const float bb = ldv_rw(biasO, o, f32m);
      float v0 = acc[i][0] + bb, v1 = acc[i][1] + bb;
      if constexpr (OUTSILU){ v0 = silu_rw(v0); v1 = silu_rw(v1); }
      *reinterpret_cast<float2*>(&outF[base]) = make_float2(v0, v1);
    }
  }
}

// ---------------- per-sample LN stats over silu(h_half) ----------------
__global__ __launch_bounds__(256) void stats_rw(const float* __restrict__ h, float* __restrict__ stats){
  const int b = blockIdx.x >> 1, half = blockIdx.x & 1;
  const float* base = h + ((b*256 + half*128) << 8);
  float s = 0.f, s2 = 0.f;
  for (int i = threadIdx.x; i < 32768; i += 256){
    float a = silu_rw(base[i]);
    s += a; s2 += a*a;
  }
  __shared__ float sh[2][256];
  sh[0][threadIdx.x] = s; sh[1][threadIdx.x] = s2;
  __syncthreads();
  for (int st = 128; st > 0; st >>= 1){
    if (threadIdx.x < st){
      sh[0][threadIdx.x] += sh[0][threadIdx.x + st];
      sh[1][threadIdx.x] += sh[1][threadIdx.x + st];
    }
    __syncthreads();
  }
  if (threadIdx.x == 0){
    float mu  = sh[0][0] * (1.f/32768.f);
    float var = sh[1][0] * (1.f/32768.f) - mu*mu;
    stats[half*32 + b]      = mu;
    stats[half*32 + 16 + b] = 1.f / sqrtf(var + 1e-5f);
  }
}

// ---------------- LN apply ----------------
__global__ __launch_bounds__(256) void ln_rw(const float* __restrict__ h,
    const void* lwp, const void* lbp, const void* lwn, const void* lbn,
    const float* __restrict__ stats, const float* __restrict__ flags,
    float* __restrict__ lnp, float* __restrict__ lnn){
  const int f32m = (flags[0] != 0.f);
  int i = blockIdx.x * 256 + threadIdx.x;
  int b = i >> 16, c = (i >> 8) & 255, p = i & 255;
  float a = silu_rw(h[i]);
  if (c < 128){
    float v = (a - stats[b]) * stats[16 + b] * ldv_rw(lwp, (c << 8) + p, f32m) + ldv_rw(lbp, (c << 8) + p, f32m);
    lnp[((b*128 + c) << 8) + p] = v;
  } else {
    int cc = c - 128;
    float v = (a - stats[32 + b]) * stats[48 + b] * ldv_rw(lwn, (cc << 8) + p, f32m) + ldv_rw(lbn, (cc << 8) + p, f32m);
    lnn[((b*128 + cc) << 8) + p] = v;
  }
}

// ---------------- VQ search v5: MFMA distance GEMM + top-2 certification ----
// Block: 4 waves, (b_local, g, half) from blockIdx. Wave: 32 vectors
// (2 A-frags of 16 consecutive pixels), all 1024 codes in 64 col-tiles.
// A = bf16 hi/lo of -2z (rows = lane&15). B streamed from global cbh/cbl
// (cols = lane&15). C init = cn[col] -> D = cn - 2 z.c. Epilogue: top-2
// (min1,argmin,min2) strict-<; 16-lane shfl merge; cert gap
// eb = 3e-4*sqrt(zn)*cmax (our bf16-split error, 25x margin)
//    + 2e-6*zn            (np reference's own f32 rounding noise, 5x margin)
// else push to fallback list (np-bit-exact recompute).
template<int LEVELS>
__global__ __launch_bounds__(256) void quantm_rw(
    const float* __restrict__ z, const short* __restrict__ cbh,
    const short* __restrict__ cbl, const float* __restrict__ cbn,
    const float* __restrict__ cmaxp, int* __restrict__ idxout,
    float* __restrict__ lossacc, int* __restrict__ cnt,
    int* __restrict__ list, int b_base)
{
  const int tid  = threadIdx.x;
  const int lane = tid & 63, wid = tid >> 6;
  const int lc = lane & 15, gq = lane >> 4;
  const int bid  = blockIdx.x;
  const int bl   = bid >> 6;          // local batch
  const int rest = bid & 63;
  const int g = rest >> 1, half = rest & 1;
  int cb, wbase, wstep;
  if (LEVELS == 4){ cb = (g & 3)*8 + (g >> 2); wbase = (g >> 2)*1024 + (g & 3); wstep = 4; }
  else            { cb = g;                    wbase = g << 8;                  wstep = 1; }
  const int pb = half*128 + wid*32;

  // ---- load z rows, build -2z hi/lo bf16 A-fragments, partial |z|^2 ----
  bf16x8 ah0, al0, ah1, al1;
  float zn0 = 0.f, zn1 = 0.f;
  const int zoff = (((bl << 10) + cb) << 8) + pb + lc;
  const int e0 = gq << 3;
  #pragma unroll
  for (int i = 0; i < 8; ++i){
    const int zo = zoff + ((e0 + i) << 13);
    const float z0 = z[zo];
    const float z1 = z[zo + 16];
    zn0 += z0*z0; zn1 += z1*z1;
    const float s0 = -2.f*z0, s1 = -2.f*z1;
    const unsigned short h0 = f2bf_rw(s0);
    const unsigned short h1 = f2bf_rw(s1);
    ah0[i] = (short)h0; al0[i] = (short)f2bf_rw(s0 - bf2f_rw(h0));
    ah1[i] = (short)h1; al1[i] = (short)f2bf_rw(s1 - bf2f_rw(h1));
  }
  zn0 += __shfl_xor(zn0, 16); zn0 += __shfl_xor(zn0, 32);   // full zn for row lc
  zn1 += __shfl_xor(zn1, 16); zn1 += __shfl_xor(zn1, 32);

  float m1[8], m2[8]; int j1[8];
  #pragma unroll
  for (int s = 0; s < 8; ++s){ m1[s] = __builtin_inff(); m2[s] = __builtin_inff(); j1[s] = 0; }

  const short* bhp = cbh + (lc << 5) + e0;
  const short* blp = cbl + (lc << 5) + e0;
  const float* cnp = cbn + lc;

  #pragma unroll 2
  for (int t = 0; t < 64; ++t){
    const int j0 = t << 4;
    const bf16x8 bh  = *reinterpret_cast<const bf16x8*>(bhp + (j0 << 5));
    const bf16x8 blo = *reinterpret_cast<const bf16x8*>(blp + (j0 << 5));
    const float cnv = cnp[j0];
    f32x4 a0 = {cnv, cnv, cnv, cnv};
    f32x4 a1 = {cnv, cnv, cnv, cnv};
    a0 = __builtin_amdgcn_mfma_f32_16x16x32_bf16(ah0, bh,  a0, 0, 0, 0);
    a0 = __builtin_amdgcn_mfma_f32_16x16x32_bf16(ah0, blo, a0, 0, 0, 0);
    a0 = __builtin_amdgcn_mfma_f32_16x16x32_bf16(al0, bh,  a0, 0, 0, 0);
    a1 = __builtin_amdgcn_mfma_f32_16x16x32_bf16(ah1, bh,  a1, 0, 0, 0);
    a1 = __builtin_amdgcn_mfma_f32_16x16x32_bf16(ah1, blo, a1, 0, 0, 0);
    a1 = __builtin_amdgcn_mfma_f32_16x16x32_bf16(al1, bh,  a1, 0, 0, 0);
    const int jc = j0 + lc;
    #pragma unroll
    for (int r = 0; r < 4; ++r){
      const float d0 = a0[r];
      m2[r] = fminf(m2[r], fmaxf(m1[r], d0));
      const bool t0 = d0 < m1[r];
      j1[r] = t0 ? jc : j1[r]; m1[r] = t0 ? d0 : m1[r];
      const float d1 = a1[r];
      m2[4+r] = fminf(m2[4+r], fmaxf(m1[4+r], d1));
      const bool t1 = d1 < m1[4+r];
      j1[4+r] = t1 ? jc : j1[4+r]; m1[4+r] = t1 ? d1 : m1[4+r];
    }
  }

  // ---- 16-lane top-2 merge (cols of each row live in one 16-lane group) ----
  #pragma unroll
  for (int k = 1; k < 16; k <<= 1){
    #pragma unroll
    for (int s = 0; s < 8; ++s){
      const float om1 = __shfl_xor(m1[s], k);
      const float om2 = __shfl_xor(m2[s], k);
      const int   oj  = __shfl_xor(j1[s], k);
      m2[s] = fminf(fminf(m2[s], om2), fmaxf(m1[s], om1));
      const bool tk = (om1 < m1[s]) || (om1 == m1[s] && oj < j1[s]);
      m1[s] = tk ? om1 : m1[s];
      j1[s] = tk ? oj  : j1[s];
    }
  }

  // ---- finalize: cert test, idx write, loss, uncertain list ----
  const float cmax = cmaxp[0];
  float lossw = 0.f;
  #pragma unroll
  for (int f = 0; f < 2; ++f){
    #pragma unroll
    for (int r = 0; r < 4; ++r){
      const int s = f*4 + r;
      const int vrow = (gq << 2) + r;
      const float znv = __shfl(f == 0 ? zn0 : zn1, vrow);
      if (lc == 0){
        const int p  = pb + f*16 + vrow;
        const int gi = (b_base + bl)*8192 + wbase + p*wstep;
        idxout[gi] = j1[s];                    // provisional if uncertain
        const float eb = fmaf(2.0e-6f, znv, 3.0e-4f * sqrtf(znv) * cmax);
        if (m2[s] - m1[s] > eb){
          lossw += znv + m1[s];
        } else {
          const int pos = atomicAdd(cnt, 1);
          list[pos] = (((bl << 5) | g) << 8) | p;
        }
      }
    }
  }
  lossw += __shfl_xor(lossw, 16);
  lossw += __shfl_xor(lossw, 32);
  if (lane == 0) atomicAdd(lossacc, lossw);
}

// ---------------- np-bit-exact f32 fallback for uncertain vectors ----------
// Replicates the reference rounding exactly: dot via ascending sequential
// fmaf (matches BLAS k-ascending FMA, r12-proven), zn via ascending
// sequential fmaf, d = (zn - 2*dot) + cn, first-min == lexicographic (d,j).
template<int LEVELS>
__global__ __launch_bounds__(256) void fb_rw(
    const float* __restrict__ z, const float* __restrict__ cb32,
    const float* __restrict__ cbn, const int* __restrict__ cnt,
    const int* __restrict__ list, int* __restrict__ idxout,
    float* __restrict__ lossacc, int b_base)
{
  const int lane = threadIdx.x & 63;
  const int wv = (blockIdx.x << 2) | (threadIdx.x >> 6);
  const int n = cnt[0];
  for (int it = wv; it < n; it += 256){
    const int id = list[it];
    const int p = id & 255, g = (id >> 8) & 31, bl = id >> 13;
    int cb, w;
    if (LEVELS == 4){ cb = (g & 3)*8 + (g >> 2); w = (g >> 2)*1024 + (p << 2) + (g & 3); }
    else            { cb = g;                    w = (g << 8) + p; }
    const int zoff = (((bl << 10) + cb) << 8) + p;
    float myz = 0.f;
    if (lane < 32) myz = z[zoff + (lane << 13)];
    // zn: sequential ascending fmaf (matches r12's accumulation order)
    float zn = 0.f;
    #pragma unroll
    for (int e = 0; e < 32; ++e){
      const float v = __shfl(myz, e);
      zn = fmaf(v, v, zn);
    }
    float bd = __builtin_inff(); int bj = 0;
    for (int j = lane; j < 1024; j += 64){
      const float* c = cb32 + (j << 5);
      float dot = 0.f;
      #pragma unroll
      for (int e = 0; e < 32; ++e) dot = fmaf(__shfl(myz, e), c[e], dot);
      const float d = (zn - 2.f*dot) + cbn[j];   // np's exact formula/rounding
      if (d < bd){ bd = d; bj = j; }
    }
    #pragma unroll
    for (int k = 1; k < 64; k <<= 1){
      const float od = __shfl_xor(bd, k);
      const int   oj = __shfl_xor(bj, k);
      if (od < bd || (od == bd && oj < bj)){ bd = od; bj = oj; }
    }
    if (lane == 0){
      idxout[(b_base + bl)*8192 + w] = bj;
      atomicAdd(lossacc, bd);                    // bd == |z-c|^2 (includes zn)
    }
  }
}

// ---------------- zq_p output (f32) ----------------
__global__ __launch_bounds__(256) void zqout_rw(const int* __restrict__ idxp,
    const float* __restrict__ cb32, float* __restrict__ out){
  int t = blockIdx.x * 256 + threadIdx.x;
  int l = t & 3, n = (t >> 2) & 2047, e = (t >> 13) & 31, b = t >> 18;
  int id = idxp[b*8192 + (n << 2) + l];
  out[t] = cb32[((id & 1023) << 5) + e];
}

// ---------------- zero hcat accum ----------------
__global__ __launch_bounds__(256) void zero_rw(float* __restrict__ p){
  p[blockIdx.x * 256 + threadIdx.x] = 0.f;
}

// ---------------- loss finalize ----------------
__global__ void loss_rw(const float* __restrict__ lossacc, float* __restrict__ out){
  if (threadIdx.x == 0 && blockIdx.x == 0)
    out[0] = 1.25f * (lossacc[0] + lossacc[1]) * (1.f/4194304.f);
}

extern "C" void kernel_launch(void* const* d_in, const int* in_sizes, int n_in,
                              void* d_out, int out_size, void* d_ws, size_t ws_size,
                              hipStream_t stream){
  (void)in_sizes; (void)n_in; (void)out_size;
  const void* x   = d_in[0];
  const void* ciw = d_in[1];
  const void* cib = d_in[2];
  const void* lwp = d_in[3];
  const void* lbp = d_in[4];
  const void* wpi = d_in[5];
  const void* bpi = d_in[6];
  const void* wpo = d_in[7];
  const void* bpo = d_in[8];
  const void* lwn = d_in[9];
  const void* lbn = d_in[10];
  const void* wni = d_in[11];
  const void* bni = d_in[12];
  const void* wno = d_in[13];
  const void* bno = d_in[14];
  const void* cbk = d_in[15];
  const void* cow = d_in[16];
  const void* cob = d_in[17];

  float* ws    = (float*)d_ws;
  float* flags = ws + FLAGS_OFF;
  float* loss  = ws + LOSS_OFF;
  float* stats = ws + STATS_OFF;
  float* cmaxp = ws + CMAX_OFF;
  float* cb32  = ws + CB32_OFF;
  float* cbn   = ws + CBN_OFF;
  int*   cnts  = (int*)(ws + CNT_OFF);
  int*   idxp  = (int*)(ws + IDXP_OFF);
  int*   idxn  = (int*)(ws + IDXN_OFF);
  short* cbh   = (short*)(ws + CBH_OFF);
  short* cbl   = (short*)(ws + CBL_OFF);
  int*   list  = (int*)(ws + LIST_OFF);
  float* R2    = ws + R2_OFF;
  float* R3    = ws + R3_OFF;
  float* R1    = ws + R1_OFF;

  float* outO = (float*)d_out;
  float* outL = outO + 1048576;
  float* outZ = outO + 1048577;

  const size_t wsf = ws_size / 4;
  int CS = 4;
  if      (wsf >= (size_t)R1_OFF + 16u*262144u) CS = 16;
  else if (wsf >= (size_t)R1_OFF +  8u*262144u) CS = 8;

  detect_rw<<<1, 256, 0, stream>>>(cbk, ws);
  cbprep_rw<<<4, 256, 0, stream>>>(cbk, flags, cb32, cbn, cbh, cbl, cmaxp);
  // h = conv_in(silu(x)) -> R1
  gemm2_rw<256,2,false,false,0><<<dim3(128,4), 256, 0, stream>>>(
      nullptr, nullptr, x, ciw, cib, nullptr, nullptr, nullptr, nullptr,
      R1, flags, 256, 256, 0, 0, 0, 0);
  stats_rw<<<32, 256, 0, stream>>>(R1, stats);
  ln_rw<<<4096, 256, 0, stream>>>(R1, lwp, lbp, lwn, lbn, stats, flags, R2, R3);
  // phylo: z chunks (R2 -> R1), MFMA quantize + np-exact fallback
  {
    int ci = 0;
    for (int c = 0; c < 16; c += CS, ++ci){
      gemm2_rw<128,0,true,false,0><<<dim3(CS*8,16), 256, 0, stream>>>(
          R2, nullptr, nullptr, wpi, bpi, nullptr, nullptr, nullptr, nullptr,
          R1, flags, 128, 1024, 0, c, 0, c);
      quantm_rw<4><<<CS*64, 256, 0, stream>>>(R1, cbh, cbl, cbn, cmaxp,
                                              idxp, loss + 0, cnts + ci, list, c);
      fb_rw<4><<<64, 256, 0, stream>>>(R1, cb32, cbn, cnts + ci, list,
                                       idxp, loss + 0, c);
    }
  }
  // non-phylo
  {
    int ci = 4;
    for (int c = 0; c < 16; c += CS, ++ci){
      gemm2_rw<128,0,true,false,0><<<dim3(CS*8,16), 256, 0, stream>>>(
          R3, nullptr, nullptr, wni, bni, nullptr, nullptr, nullptr, nullptr,
          R1, flags, 128, 1024, 0, c, 0, c);
      quantm_rw<1><<<CS*64, 256, 0, stream>>>(R1, cbh, cbl, cbn, cmaxp,
                                              idxn, loss + 1, cnts + ci, list, c);
      fb_rw<1><<<64, 256, 0, stream>>>(R1, cb32, cbn, cnts + ci, list,
                                       idxn, loss + 1, c);
    }
  }
  zqout_rw<<<16384, 256, 0, stream>>>(idxp, cb32, outZ);
  // hcat accum := 0 (R2 and R3 are contiguous: 4096*256 = 1048576 floats)
  zero_rw<<<4096, 256, 0, stream>>>(R2);
  // hout_p / hout_n: fused gather + split-K x4, atomic accum
  gemm2_rw<256,3,false,true,4><<<dim3(128,2,4), 256, 0, stream>>>(
      nullptr, nullptr, nullptr, wpo, nullptr, nullptr, nullptr, idxp, cb32,
      R2, flags, 1024, 128, 0, 0, 0, 0);
  gemm2_rw<256,3,false,true,1><<<dim3(128,2,4), 256, 0, stream>>>(
      nullptr, nullptr, nullptr, wno, nullptr, nullptr, nullptr, idxn, cb32,
      R3, flags, 1024, 128, 0, 0, 0, 0);
  // out = conv_out(silu(hcat + hout_bias))
  gemm2_rw<256,5,false,false,0><<<dim3(128,4), 256, 0, stream>>>(
      R2, R3, nullptr, cow, cob, bpo, bno, nullptr, nullptr,
      outO, flags, 256, 256, 0, 0, 0, 0);
  loss_rw<<<1, 64, 0, stream>>>(loss, outL);
}

// Round 4
// 663.905 us; speedup vs baseline: 1.0294x; 1.0294x over previous
//
#include <hip/hip_runtime.h>
#include <hip/hip_bf16.h>

// Round 16: resubmit of r15 (bench infra failed twice; no kernel signal).
// r15 design, audited: quantm v6 — latency-stall fix. r14 counters:
// quantm 100us, MfmaUtil 10%, VALUBusy 37%, Occ 29%, HBM 1.4% -> nothing
// saturated = latency-bound (L2 load -> 3-dep-MFMA chain -> top-2
// epilogue, 1-tile prefetch, low occupancy). Fix: (1) 8-wave blocks:
// waves 0-3 px-groups x codes 0-511, waves 4-7 same px x codes 512-1023
// (32 tiles/wave), cross-wave top-2 merge via LDS (strict < keeps
// lower-half j == np first-min); 16->24 waves/CU via launch_bounds(512,6).
// (2) explicit next-tile register prefetch (clamped index, branchless).
// (3) fmed3(d,m1,m2) second-min update; cbh/cbl interleaved in one table
// (hi +0 / lo +512 shorts per 2KB tile) -> one base addr + imm offsets.
// Cert/fallback semantics identical to r14 (passed). All non-quant
// kernels unchanged.
// Outputs (f32): out[1048576] | loss[1] | zq_p[4194304].

typedef float f32x4  __attribute__((ext_vector_type(4)));
typedef short bf16x8 __attribute__((ext_vector_type(8)));

__device__ __forceinline__ float silu_rw(float x){ return x / (1.f + expf(-x)); }
__device__ __forceinline__ float b2f_rw(__hip_bfloat16 v){ return __bfloat162float(v); }
__device__ __forceinline__ float ldv_rw(const void* p, int i, int f32m){
  if (f32m) return ((const float*)p)[i];
  return b2f_rw(((const __hip_bfloat16*)p)[i]);
}
__device__ __forceinline__ unsigned short f2bf_rw(float x){   // f32 -> bf16 RNE
  unsigned u = __float_as_uint(x);
  unsigned r = ((u >> 16) & 1u) + 0x7FFFu;
  return (unsigned short)((u + r) >> 16);
}
__device__ __forceinline__ float bf2f_rw(unsigned short h){
  return __uint_as_float(((unsigned)h) << 16);
}

// ---------------- workspace layout (float offsets) ----------------
#define FLAGS_OFF 0
#define LOSS_OFF  4
#define STATS_OFF 8
#define CNT_OFF   72         // 8 ints: fallback counters per chunk
#define CMAX_OFF  80         // max_j |c_j| (f32)
#define CB32_OFF  128        // 1024x32 f32
#define CBN_OFF   32896      // 1024
#define IDXP_OFF  33984      // 131072 int
#define IDXN_OFF  165056     // 131072 int
#define CBHL_OFF  296192     // interleaved hi/lo bf16 table (32768 f32 slots)
#define LIST_OFF  328960     // 131072 int (uncertain list, reused per chunk)
#define R2_OFF    460032     // lnp -> hcat_p accum (524288)
#define R3_OFF    984320     // lnn -> hcat_n accum (524288)
#define R1_OFF    1508608    // h (1048576) / z chunks (CS*262144)

// ---------------- input dtype probe + zero accumulators ----------------
__global__ __launch_bounds__(256) void detect_rw(const void* cbv, float* wsb){
  __shared__ int bad;
  if (threadIdx.x == 0) bad = 0;
  __syncthreads();
  const unsigned short* u = (const unsigned short*)cbv;
  int local = 0;
  for (int i = threadIdx.x; i < 32768; i += 256){
    unsigned e = (u[i] >> 7) & 0xFF;
    if (e >= 126) local = 1;
  }
  if (local) bad = 1;
  __syncthreads();
  if (threadIdx.x == 0){
    wsb[FLAGS_OFF] = bad ? 1.f : 0.f;   // 1.0 => inputs are f32
    wsb[LOSS_OFF] = 0.f; wsb[LOSS_OFF + 1] = 0.f;
    int* c = (int*)(wsb + CNT_OFF);
    #pragma unroll
    for (int k = 0; k < 8; ++k) c[k] = 0;
    wsb[CMAX_OFF] = 0.f;
  }
}

// ------ codebook -> f32 + |c|^2 + interleaved bf16 hi/lo tile table ------
// Tile T = j>>4 occupies shorts [T*1024, T*1024+1024): hi of code j elem e
// at T*1024 + (j&15)*32 + e, lo at +512.
__global__ __launch_bounds__(256) void cbprep_rw(const void* cbv, const float* flags,
                                                 float* cb32, float* cbn,
                                                 short* cbhl, float* cmaxp){
  const int f32m = (flags[0] != 0.f);
  int j = blockIdx.x * 256 + threadIdx.x;
  if (j < 1024){
    float s = 0.f;
    const int tb = ((j >> 4) << 10) + ((j & 15) << 5);
    for (int e = 0; e < 32; ++e){
      float v = ldv_rw(cbv, j*32 + e, f32m);
      cb32[j*32 + e] = v;
      unsigned short h = f2bf_rw(v);
      cbhl[tb + e]       = (short)h;
      cbhl[tb + e + 512] = (short)f2bf_rw(v - bf2f_rw(h));
      s += v*v;
    }
    cbn[j] = s;
    atomicMax((int*)cmaxp, __float_as_int(sqrtf(s)));  // positive floats: int-bit monotone
  }
}

// ---------------- gemm2 (r11, verified): 32px x 64out tiles ----------------
template<int KCH, int INMODE, bool OUTSILU, bool ATOMIC, int LEVELS>
__global__ __launch_bounds__(256) void gemm2_rw(
    const float* __restrict__ inF, const float* __restrict__ inF2,
    const void* __restrict__ inV,
    const void* __restrict__ W, const void* __restrict__ biasO,
    const void* __restrict__ sbA, const void* __restrict__ sbB,
    const int* __restrict__ idxin, const float* __restrict__ cb32,
    float* __restrict__ outF, const float* __restrict__ flags,
    int KDIM, int OUTC, int o_off, int b_base, int ib_sub, int ob_sub)
{
  __shared__ float As[32][32];
  __shared__ float Bs[32][68];
  __shared__ int   IdxS[32][32];

  const int f32m = (flags[0] != 0.f);
  const int t  = threadIdx.x;
  const int q0 = (blockIdx.x << 5) + (b_base << 8);
  const int b  = q0 >> 8;
  const int p0 = q0 & 255;
  const int o0 = blockIdx.y << 6;
  const int k0base = blockIdx.z * KCH;
  const int tx = t & 15, ty = t >> 4;
  float acc[4][2] = {};

  const int sch = t >> 3, spx = (t & 7) << 2;

  if constexpr (INMODE == 3){
    #pragma unroll
    for (int j = 0; j < 4; ++j){
      const int p = p0 + spx + j;
      if constexpr (LEVELS == 4){
        const int l = sch >> 3, kp = sch & 7;
        IdxS[sch][spx + j] = idxin[b*8192 + (((kp << 8) + p) << 2) + l];
      } else {
        IdxS[sch][spx + j] = idxin[b*8192 + (sch << 8) + p];
      }
    }
    __syncthreads();
  }

  for (int kc = 0; kc < KCH; kc += 32){
    const int k0 = k0base + kc;
    if constexpr (INMODE == 0){
      const float4 v = *reinterpret_cast<const float4*>(
          &inF[(((b - ib_sub)*KDIM + k0 + sch) << 8) + p0 + spx]);
      *reinterpret_cast<float4*>(&As[sch][spx]) = v;
    } else if constexpr (INMODE == 2){
      if (f32m){
        const float* xf = (const float*)inV;
        float4 v = *reinterpret_cast<const float4*>(&xf[((b*KDIM + k0 + sch) << 8) + p0 + spx]);
        v.x = silu_rw(v.x); v.y = silu_rw(v.y); v.z = silu_rw(v.z); v.w = silu_rw(v.w);
        *reinterpret_cast<float4*>(&As[sch][spx]) = v;
      } else {
        const __hip_bfloat16* xb = (const __hip_bfloat16*)inV;
        const int off = ((b*KDIM + k0 + sch) << 8) + p0 + spx;
        #pragma unroll
        for (int j = 0; j < 4; ++j) As[sch][spx + j] = silu_rw(b2f_rw(xb[off + j]));
      }
    } else if constexpr (INMODE == 3){
      const int e = k0 >> 5;
      #pragma unroll
      for (int j = 0; j < 4; ++j)
        As[sch][spx + j] = cb32[((IdxS[sch][spx + j] & 1023) << 5) + e];
    } else { // INMODE 5
      const float* src = (k0 < 128) ? inF : inF2;
      const void* sb   = (k0 < 128) ? sbA : sbB;
      const int kh = k0 & 127;
      const float bb = ldv_rw(sb, kh + sch, f32m);
      float4 v = *reinterpret_cast<const float4*>(&src[((b*128 + kh + sch) << 8) + p0 + spx]);
      v.x = silu_rw(v.x + bb); v.y = silu_rw(v.y + bb);
      v.z = silu_rw(v.z + bb); v.w = silu_rw(v.w + bb);
      *reinterpret_cast<float4*>(&As[sch][spx]) = v;
    }
    if (f32m){
      const float* Wf = (const float*)W;
      #pragma unroll
      for (int r = 0; r < 8; ++r){
        int ii = t + (r << 8); int oo = ii >> 5, cc = ii & 31;
        Bs[cc][oo] = Wf[(o0 + oo)*KDIM + k0 + cc];
      }
    } else {
      const __hip_bfloat16* Wb = (const __hip_bfloat16*)W;
      #pragma unroll
      for (int r = 0; r < 8; ++r){
        int ii = t + (r << 8); int oo = ii >> 5, cc = ii & 31;
        Bs[cc][oo] = b2f_rw(Wb[(o0 + oo)*KDIM + k0 + cc]);
      }
    }
    __syncthreads();
    #pragma unroll
    for (int kk = 0; kk < 32; ++kk){
      const float2 a = *reinterpret_cast<const float2*>(&As[kk][tx << 1]);
      const float4 w = *reinterpret_cast<const float4*>(&Bs[kk][ty << 2]);
      acc[0][0] += w.x*a.x; acc[0][1] += w.x*a.y;
      acc[1][0] += w.y*a.x; acc[1][1] += w.y*a.y;
      acc[2][0] += w.z*a.x; acc[2][1] += w.z*a.y;
      acc[3][0] += w.w*a.x; acc[3][1] += w.w*a.y;
    }
    __syncthreads();
  }
  #pragma unroll
  for (int i = 0; i < 4; ++i){
    const int o = o0 + (ty << 2) + i;
    const int base = (((b - ob_sub)*OUTC + o_off + o) << 8) + p0 + (tx << 1);
    if constexpr (ATOMIC){
      atomicAdd(&outF[base + 0], acc[i][0]);
      atomicAdd(&outF[base + 1], acc[i][1]);
    } else {
      const float bb = ldv_rw(biasO, o, f32m);
      float v0 = acc[i][0] + bb, v1 = acc[i][1] + bb;
      if constexpr (OUTSILU){ v0 = silu_rw(v0); v1 = silu_rw(v1); }
      *reinterpret_cast<float2*>(&outF[base]) = make_float2(v0, v1);
    }
  }
}

// ---------------- per-sample LN stats over silu(h_half) ----------------
__global__ __launch_bounds__(256) void stats_rw(const float* __restrict__ h, float* __restrict__ stats){
  const int b = blockIdx.x >> 1, half = blockIdx.x & 1;
  const float* base = h + ((b*256 + half*128) << 8);
  float s = 0.f, s2 = 0.f;
  for (int i = threadIdx.x; i < 32768; i += 256){
    float a = silu_rw(base[i]);
    s += a; s2 += a*a;
  }
  __shared__ float sh[2][256];
  sh[0][threadIdx.x] = s; sh[1][threadIdx.x] = s2;
  __syncthreads();
  for (int st = 128; st > 0; st >>= 1){
    if (threadIdx.x < st){
      sh[0][threadIdx.x] += sh[0][threadIdx.x + st];
      sh[1][threadIdx.x] += sh[1][threadIdx.x + st];
    }
    __syncthreads();
  }
  if (threadIdx.x == 0){
    float mu  = sh[0][0] * (1.f/32768.f);
    float var = sh[1][0] * (1.f/32768.f) - mu*mu;
    stats[half*32 + b]      = mu;
    stats[half*32 + 16 + b] = 1.f / sqrtf(var + 1e-5f);
  }
}

// ---------------- LN apply ----------------
__global__ __launch_bounds__(256) void ln_rw(const float* __restrict__ h,
    const void* lwp, const void* lbp, const void* lwn, const void* lbn,
    const float* __restrict__ stats, const float* __restrict__ flags,
    float* __restrict__ lnp, float* __restrict__ lnn){
  const int f32m = (flags[0] != 0.f);
  int i = blockIdx.x * 256 + threadIdx.x;
  int b = i >> 16, c = (i >> 8) & 255, p = i & 255;
  float a = silu_rw(h[i]);
  if (c < 128){
    float v = (a - stats[b]) * stats[16 + b] * ldv_rw(lwp, (c << 8) + p, f32m) + ldv_rw(lbp, (c << 8) + p, f32m);
    lnp[((b*128 + c) << 8) + p] = v;
  } else {
    int cc = c - 128;
    float v = (a - stats[32 + b]) * stats[48 + b] * ldv_rw(lwn, (cc << 8) + p, f32m) + ldv_rw(lbn, (cc << 8) + p, f32m);
    lnn[((b*128 + cc) << 8) + p] = v;
  }
}

// ---------------- VQ search v6: 8-wave MFMA + prefetch + LDS merge ----------
// Block: 512 thr = 8 waves. Wave w: pixel group (w&3), code half (w>>2)
// (32 tiles of 16 codes). Per wave: 2 A-frags (32 px), prefetched B-frags
// from interleaved cbhl (hi +0 / lo +512 shorts per 2KB tile), C init =
// cn[col] -> D = cn - 2 z.c. Top-2 via fmed3; 16-lane shfl merge; cross-
// wave merge via LDS (strict < keeps lower-half j == np first-argmin).
// Cert eb = 3e-4*sqrt(zn)*cmax + 2e-6*zn, else np-bit-exact fallback.
template<int LEVELS>
__global__ __launch_bounds__(512, 6) void quantm_rw(
    const float* __restrict__ z, const short* __restrict__ cbhl,
    const float* __restrict__ cbn, const float* __restrict__ cmaxp,
    int* __restrict__ idxout, float* __restrict__ lossacc,
    int* __restrict__ cnt, int* __restrict__ list, int b_base)
{
  __shared__ float mgm1[4][4][8], mgm2[4][4][8];
  __shared__ int   mgj [4][4][8];
  __shared__ float red[4];

  const int tid  = threadIdx.x;
  const int lane = tid & 63, wid = tid >> 6;
  const int lc = lane & 15, gq = lane >> 4;
  const int pg = wid & 3, ch = wid >> 2;    // pixel group, code half
  const int bid  = blockIdx.x;
  const int bl   = bid >> 6;                // local batch
  const int rest = bid & 63;
  const int g = rest >> 1, half = rest & 1;
  int cb, wbase, wstep;
  if (LEVELS == 4){ cb = (g & 3)*8 + (g >> 2); wbase = (g >> 2)*1024 + (g & 3); wstep = 4; }
  else            { cb = g;                    wbase = g << 8;                  wstep = 1; }
  const int pb = half*128 + pg*32;

  // ---- load z rows, build -2z hi/lo bf16 A-fragments, partial |z|^2 ----
  bf16x8 ah0, al0, ah1, al1;
  float zn0 = 0.f, zn1 = 0.f;
  const int zoff = (((bl << 10) + cb) << 8) + pb + lc;
  const int e0 = gq << 3;
  #pragma unroll
  for (int i = 0; i < 8; ++i){
    const int zo = zoff + ((e0 + i) << 13);
    const float z0 = z[zo];
    const float z1 = z[zo + 16];
    zn0 += z0*z0; zn1 += z1*z1;
    const float s0 = -2.f*z0, s1 = -2.f*z1;
    const unsigned short h0 = f2bf_rw(s0);
    const unsigned short h1 = f2bf_rw(s1);
    ah0[i] = (short)h0; al0[i] = (short)f2bf_rw(s0 - bf2f_rw(h0));
    ah1[i] = (short)h1; al1[i] = (short)f2bf_rw(s1 - bf2f_rw(h1));
  }
  zn0 += __shfl_xor(zn0, 16); zn0 += __shfl_xor(zn0, 32);   // full zn for row lc
  zn1 += __shfl_xor(zn1, 16); zn1 += __shfl_xor(zn1, 32);

  float m1[8], m2[8]; int j1[8];
  #pragma unroll
  for (int s = 0; s < 8; ++s){ m1[s] = __builtin_inff(); m2[s] = __builtin_inff(); j1[s] = 0; }

  // interleaved table: wave's tiles T = ch*32 + t; shorts base:
  const short* bp  = cbhl + (ch << 15) + (lc << 5) + (gq << 3);
  const float* cnp = cbn + (ch << 9) + lc;

  bf16x8 bh  = *reinterpret_cast<const bf16x8*>(bp);
  bf16x8 blo = *reinterpret_cast<const bf16x8*>(bp + 512);
  float  cnv = cnp[0];

  #pragma unroll 2
  for (int t = 0; t < 32; ++t){
    const int tn = (t < 31) ? t + 1 : 31;      // clamped prefetch index
    const bf16x8 bhn  = *reinterpret_cast<const bf16x8*>(bp + (tn << 10));
    const bf16x8 blon = *reinterpret_cast<const bf16x8*>(bp + (tn << 10) + 512);
    const float  cnn  = cnp[tn << 4];

    f32x4 a0 = {cnv, cnv, cnv, cnv};
    f32x4 a1 = {cnv, cnv, cnv, cnv};
    a0 = __builtin_amdgcn_mfma_f32_16x16x32_bf16(ah0, bh,  a0, 0, 0, 0);
    a0 = __builtin_amdgcn_mfma_f32_16x16x32_bf16(ah0, blo, a0, 0, 0, 0);
    a0 = __builtin_amdgcn_mfma_f32_16x16x32_bf16(al0, bh,  a0, 0, 0, 0);
    a1 = __builtin_amdgcn_mfma_f32_16x16x32_bf16(ah1, bh,  a1, 0, 0, 0);
    a1 = __builtin_amdgcn_mfma_f32_16x16x32_bf16(ah1, blo, a1, 0, 0, 0);
    a1 = __builtin_amdgcn_mfma_f32_16x16x32_bf16(al1, bh,  a1, 0, 0, 0);

    const int jc = (((ch << 5) + t) << 4) + lc;
    #pragma unroll
    for (int r = 0; r < 4; ++r){
      const float d0 = a0[r];
      m2[r] = __builtin_amdgcn_fmed3f(d0, m1[r], m2[r]);
      const bool t0 = d0 < m1[r];
      j1[r] = t0 ? jc : j1[r]; m1[r] = t0 ? d0 : m1[r];
      const float d1 = a1[r];
      m2[4+r] = __builtin_amdgcn_fmed3f(d1, m1[4+r], m2[4+r]);
      const bool t1 = d1 < m1[4+r];
      j1[4+r] = t1 ? jc : j1[4+r]; m1[4+r] = t1 ? d1 : m1[4+r];
    }
    bh = bhn; blo = blon; cnv = cnn;
  }

  // ---- 16-lane top-2 merge (cols of each row live in one 16-lane group) ----
  #pragma unroll
  for (int k = 1; k < 16; k <<= 1){
    #pragma unroll
    for (int s = 0; s < 8; ++s){
      const float om1 = __shfl_xor(m1[s], k);
      const float om2 = __shfl_xor(m2[s], k);
      const int   oj  = __shfl_xor(j1[s], k);
      m2[s] = fminf(fminf(m2[s], om2), fmaxf(m1[s], om1));
      const bool tk = (om1 < m1[s]) || (om1 == m1[s] && oj < j1[s]);
      m1[s] = tk ? om1 : m1[s];
      j1[s] = tk ? oj  : j1[s];
    }
  }

  // ---- cross-wave merge: upper code-half -> LDS, lower merges ----
  if (wid >= 4 && lc == 0){
    #pragma unroll
    for (int s = 0; s < 8; ++s){
      mgm1[wid-4][gq][s] = m1[s];
      mgm2[wid-4][gq][s] = m2[s];
      mgj [wid-4][gq][s] = j1[s];
    }
  }
  __syncthreads();
  if (wid < 4){
    #pragma unroll
    for (int s = 0; s < 8; ++s){
      const float om1 = mgm1[wid][gq][s];
      const float om2 = mgm2[wid][gq][s];
      const int   oj  = mgj [wid][gq][s];
      m2[s] = fminf(fminf(m2[s], om2), fmaxf(m1[s], om1));
      const bool tk = om1 < m1[s];       // tie keeps lower half (smaller j)
      m1[s] = tk ? om1 : m1[s];
      j1[s] = tk ? oj  : j1[s];
    }

    // ---- finalize: cert test, idx write, loss, uncertain list ----
    const float cmax = cmaxp[0];
    float lossw = 0.f;
    #pragma unroll
    for (int f = 0; f < 2; ++f){
      #pragma unroll
      for (int r = 0; r < 4; ++r){
        const int s = f*4 + r;
        const int vrow = (gq << 2) + r;
        const float znv = __shfl(f == 0 ? zn0 : zn1, vrow);
        if (lc == 0){
          const int p  = pb + f*16 + vrow;
          const int gi = (b_base + bl)*8192 + wbase + p*wstep;
          idxout[gi] = j1[s];                    // provisional if uncertain
          const float eb = fmaf(2.0e-6f, znv, 3.0e-4f * sqrtf(znv) * cmax);
          if (m2[s] - m1[s] > eb){
            lossw += znv + m1[s];
          } else {
            const int pos = atomicAdd(cnt, 1);
            if (pos < 131072) list[pos] = (((bl << 5) | g) << 8) | p;
          }
        }
      }
    }
    lossw += __shfl_xor(lossw, 16);
    lossw += __shfl_xor(lossw, 32);
    if (lane == 0) red[wid] = lossw;
  }
  __syncthreads();
  if (tid == 0) atomicAdd(lossacc, red[0] + red[1] + red[2] + red[3]);
}

// ---------------- np-bit-exact f32 fallback for uncertain vectors ----------
// Replicates the reference rounding exactly: dot via ascending sequential
// fmaf (matches BLAS k-ascending FMA, r12-proven), zn via ascending
// sequential fmaf, d = (zn - 2*dot) + cn, first-min == lexicographic (d,j).
template<int LEVELS>
__global__ __launch_bounds__(256) void fb_rw(
    const float* __restrict__ z, const float* __restrict__ cb32,
    const float* __restrict__ cbn, const int* __restrict__ cnt,
    const int* __restrict__ list, int* __restrict__ idxout,
    float* __restrict__ lossacc, int b_base)
{
  const int lane = threadIdx.x & 63;
  const int wv = (blockIdx.x << 2) | (threadIdx.x >> 6);
  int n = cnt[0];
  if (n > 131072) n = 131072;
  for (int it = wv; it < n; it += 256){
    const int id = list[it];
    const int p = id & 255, g = (id >> 8) & 31, bl = id >> 13;
    int cb, w;
    if (LEVELS == 4){ cb = (g & 3)*8 + (g >> 2); w = (g >> 2)*1024 + (p << 2) + (g & 3); }
    else            { cb = g;                    w = (g << 8) + p; }
    const int zoff = (((bl << 10) + cb) << 8) + p;
    float myz = 0.f;
    if (lane < 32) myz = z[zoff + (lane << 13)];
    // zn: sequential ascending fmaf (matches np's accumulation order)
    float zn = 0.f;
    #pragma unroll
    for (int e = 0; e < 32; ++e){
      const float v = __shfl(myz, e);
      zn = fmaf(v, v, zn);
    }
    float bd = __builtin_inff(); int bj = 0;
    for (int j = lane; j < 1024; j += 64){
      const float* c = cb32 + (j << 5);
      float dot = 0.f;
      #pragma unroll
      for (int e = 0; e < 32; ++e) dot = fmaf(__shfl(myz, e), c[e], dot);
      const float d = (zn - 2.f*dot) + cbn[j];   // np's exact formula/rounding
      if (d < bd){ bd = d; bj = j; }
    }
    #pragma unroll
    for (int k = 1; k < 64; k <<= 1){
      const float od = __shfl_xor(bd, k);
      const int   oj = __shfl_xor(bj, k);
      if (od < bd || (od == bd && oj < bj)){ bd = od; bj = oj; }
    }
    if (lane == 0){
      idxout[(b_base + bl)*8192 + w] = bj;
      atomicAdd(lossacc, bd);                    // bd == |z-c|^2 (includes zn)
    }
  }
}

// ---------------- zq_p output (f32) ----------------
__global__ __launch_bounds__(256) void zqout_rw(const int* __restrict__ idxp,
    const float* __restrict__ cb32, float* __restrict__ out){
  int t = blockIdx.x * 256 + threadIdx.x;
  int l = t & 3, n = (t >> 2) & 2047, e = (t >> 13) & 31, b = t >> 18;
  int id = idxp[b*8192 + (n << 2) + l];
  out[t] = cb32[((id & 1023) << 5) + e];
}

// ---------------- zero hcat accum ----------------
__global__ __launch_bounds__(256) void zero_rw(float* __restrict__ p){
  p[blockIdx.x * 256 + threadIdx.x] = 0.f;
}

// ---------------- loss finalize ----------------
__global__ void loss_rw(const float* __restrict__ lossacc, float* __restrict__ out){
  if (threadIdx.x == 0 && blockIdx.x == 0)
    out[0] = 1.25f * (lossacc[0] + lossacc[1]) * (1.f/4194304.f);
}

extern "C" void kernel_launch(void* const* d_in, const int* in_sizes, int n_in,
                              void* d_out, int out_size, void* d_ws, size_t ws_size,
                              hipStream_t stream){
  (void)in_sizes; (void)n_in; (void)out_size;
  const void* x   = d_in[0];
  const void* ciw = d_in[1];
  const void* cib = d_in[2];
  const void* lwp = d_in[3];
  const void* lbp = d_in[4];
  const void* wpi = d_in[5];
  const void* bpi = d_in[6];
  const void* wpo = d_in[7];
  const void* bpo = d_in[8];
  const void* lwn = d_in[9];
  const void* lbn = d_in[10];
  const void* wni = d_in[11];
  const void* bni = d_in[12];
  const void* wno = d_in[13];
  const void* bno = d_in[14];
  const void* cbk = d_in[15];
  const void* cow = d_in[16];
  const void* cob = d_in[17];

  float* ws    = (float*)d_ws;
  float* flags = ws + FLAGS_OFF;
  float* loss  = ws + LOSS_OFF;
  float* stats = ws + STATS_OFF;
  float* cmaxp = ws + CMAX_OFF;
  float* cb32  = ws + CB32_OFF;
  float* cbn   = ws + CBN_OFF;
  int*   cnts  = (int*)(ws + CNT_OFF);
  int*   idxp  = (int*)(ws + IDXP_OFF);
  int*   idxn  = (int*)(ws + IDXN_OFF);
  short* cbhl  = (short*)(ws + CBHL_OFF);
  int*   list  = (int*)(ws + LIST_OFF);
  float* R2    = ws + R2_OFF;
  float* R3    = ws + R3_OFF;
  float* R1    = ws + R1_OFF;

  float* outO = (float*)d_out;
  float* outL = outO + 1048576;
  float* outZ = outO + 1048577;

  const size_t wsf = ws_size / 4;
  int CS = 4;
  if      (wsf >= (size_t)R1_OFF + 16u*262144u) CS = 16;
  else if (wsf >= (size_t)R1_OFF +  8u*262144u) CS = 8;

  detect_rw<<<1, 256, 0, stream>>>(cbk, ws);
  cbprep_rw<<<4, 256, 0, stream>>>(cbk, flags, cb32, cbn, cbhl, cmaxp);
  // h = conv_in(silu(x)) -> R1
  gemm2_rw<256,2,false,false,0><<<dim3(128,4), 256, 0, stream>>>(
      nullptr, nullptr, x, ciw, cib, nullptr, nullptr, nullptr, nullptr,
      R1, flags, 256, 256, 0, 0, 0, 0);
  stats_rw<<<32, 256, 0, stream>>>(R1, stats);
  ln_rw<<<4096, 256, 0, stream>>>(R1, lwp, lbp, lwn, lbn, stats, flags, R2, R3);
  // phylo: z chunks (R2 -> R1), MFMA quantize + np-exact fallback
  {
    int ci = 0;
    for (int c = 0; c < 16; c += CS, ++ci){
      gemm2_rw<128,0,true,false,0><<<dim3(CS*8,16), 256, 0, stream>>>(
          R2, nullptr, nullptr, wpi, bpi, nullptr, nullptr, nullptr, nullptr,
          R1, flags, 128, 1024, 0, c, 0, c);
      quantm_rw<4><<<CS*64, 512, 0, stream>>>(R1, cbhl, cbn, cmaxp,
                                              idxp, loss + 0, cnts + ci, list, c);
      fb_rw<4><<<64, 256, 0, stream>>>(R1, cb32, cbn, cnts + ci, list,
                                       idxp, loss + 0, c);
    }
  }
  // non-phylo
  {
    int ci = 4;
    for (int c = 0; c < 16; c += CS, ++ci){
      gemm2_rw<128,0,true,false,0><<<dim3(CS*8,16), 256, 0, stream>>>(
          R3, nullptr, nullptr, wni, bni, nullptr, nullptr, nullptr, nullptr,
          R1, flags, 128, 1024, 0, c, 0, c);
      quantm_rw<1><<<CS*64, 512, 0, stream>>>(R1, cbhl, cbn, cmaxp,
                                              idxn, loss + 1, cnts + ci, list, c);
      fb_rw<1><<<64, 256, 0, stream>>>(R1, cb32, cbn, cnts + ci, list,
                                       idxn, loss + 1, c);
    }
  }
  zqout_rw<<<16384, 256, 0, stream>>>(idxp, cb32, outZ);
  // hcat accum := 0 (R2 and R3 are contiguous: 4096*256 = 1048576 floats)
  zero_rw<<<4096, 256, 0, stream>>>(R2);
  // hout_p / hout_n: fused gather + split-K x4, atomic accum
  gemm2_rw<256,3,false,true,4><<<dim3(128,2,4), 256, 0, stream>>>(
      nullptr, nullptr, nullptr, wpo, nullptr, nullptr, nullptr, idxp, cb32,
      R2, flags, 1024, 128, 0, 0, 0, 0);
  gemm2_rw<256,3,false,true,1><<<dim3(128,2,4), 256, 0, stream>>>(
      nullptr, nullptr, nullptr, wno, nullptr, nullptr, nullptr, idxn, cb32,
      R3, flags, 1024, 128, 0, 0, 0, 0);
  // out = conv_out(silu(hcat + hout_bias))
  gemm2_rw<256,5,false,false,0><<<dim3(128,4), 256, 0, stream>>>(
      R2, R3, nullptr, cow, cob, bpo, bno, nullptr, nullptr,
      outO, flags, 256, 256, 0, 0, 0, 0);
  loss_rw<<<1, 64, 0, stream>>>(loss, outL);
}

// Round 5
// 604.644 us; speedup vs baseline: 1.1303x; 1.0980x over previous
//
#include <hip/hip_runtime.h>
#include <hip/hip_bf16.h>

// Round 17: kill the scratch spill. r16 counters: quantm WRITE_SIZE 54.6MB
// (legit writes ~0.6MB) = 104 B/thread scratch spill; FETCH 25.7 vs ~17MB
// legit. Cause: launch_bounds(512,6) caps VGPR at 85; prefetch + unroll-2
// needs ~100 live regs -> ~26 spilled INTO the inner loop (scratch fills
// at L2 latency each tile). Occupancy rose 29->40% but waves just wait on
// scratch vmcnt -> dur unchanged 98us. Fix: launch_bounds(512,4) -> cap
// 128 VGPR, no spill, 2 blocks/CU. Single-variable change vs r16 (passed).
// Outputs (f32): out[1048576] | loss[1] | zq_p[4194304].

typedef float f32x4  __attribute__((ext_vector_type(4)));
typedef short bf16x8 __attribute__((ext_vector_type(8)));

__device__ __forceinline__ float silu_rw(float x){ return x / (1.f + expf(-x)); }
__device__ __forceinline__ float b2f_rw(__hip_bfloat16 v){ return __bfloat162float(v); }
__device__ __forceinline__ float ldv_rw(const void* p, int i, int f32m){
  if (f32m) return ((const float*)p)[i];
  return b2f_rw(((const __hip_bfloat16*)p)[i]);
}
__device__ __forceinline__ unsigned short f2bf_rw(float x){   // f32 -> bf16 RNE
  unsigned u = __float_as_uint(x);
  unsigned r = ((u >> 16) & 1u) + 0x7FFFu;
  return (unsigned short)((u + r) >> 16);
}
__device__ __forceinline__ float bf2f_rw(unsigned short h){
  return __uint_as_float(((unsigned)h) << 16);
}

// ---------------- workspace layout (float offsets) ----------------
#define FLAGS_OFF 0
#define LOSS_OFF  4
#define STATS_OFF 8
#define CNT_OFF   72         // 8 ints: fallback counters per chunk
#define CMAX_OFF  80         // max_j |c_j| (f32)
#define CB32_OFF  128        // 1024x32 f32
#define CBN_OFF   32896      // 1024
#define IDXP_OFF  33984      // 131072 int
#define IDXN_OFF  165056     // 131072 int
#define CBHL_OFF  296192     // interleaved hi/lo bf16 table (32768 f32 slots)
#define LIST_OFF  328960     // 131072 int (uncertain list, reused per chunk)
#define R2_OFF    460032     // lnp -> hcat_p accum (524288)
#define R3_OFF    984320     // lnn -> hcat_n accum (524288)
#define R1_OFF    1508608    // h (1048576) / z chunks (CS*262144)

// ---------------- input dtype probe + zero accumulators ----------------
__global__ __launch_bounds__(256) void detect_rw(const void* cbv, float* wsb){
  __shared__ int bad;
  if (threadIdx.x == 0) bad = 0;
  __syncthreads();
  const unsigned short* u = (const unsigned short*)cbv;
  int local = 0;
  for (int i = threadIdx.x; i < 32768; i += 256){
    unsigned e = (u[i] >> 7) & 0xFF;
    if (e >= 126) local = 1;
  }
  if (local) bad = 1;
  __syncthreads();
  if (threadIdx.x == 0){
    wsb[FLAGS_OFF] = bad ? 1.f : 0.f;   // 1.0 => inputs are f32
    wsb[LOSS_OFF] = 0.f; wsb[LOSS_OFF + 1] = 0.f;
    int* c = (int*)(wsb + CNT_OFF);
    #pragma unroll
    for (int k = 0; k < 8; ++k) c[k] = 0;
    wsb[CMAX_OFF] = 0.f;
  }
}

// ------ codebook -> f32 + |c|^2 + interleaved bf16 hi/lo tile table ------
// Tile T = j>>4 occupies shorts [T*1024, T*1024+1024): hi of code j elem e
// at T*1024 + (j&15)*32 + e, lo at +512.
__global__ __launch_bounds__(256) void cbprep_rw(const void* cbv, const float* flags,
                                                 float* cb32, float* cbn,
                                                 short* cbhl, float* cmaxp){
  const int f32m = (flags[0] != 0.f);
  int j = blockIdx.x * 256 + threadIdx.x;
  if (j < 1024){
    float s = 0.f;
    const int tb = ((j >> 4) << 10) + ((j & 15) << 5);
    for (int e = 0; e < 32; ++e){
      float v = ldv_rw(cbv, j*32 + e, f32m);
      cb32[j*32 + e] = v;
      unsigned short h = f2bf_rw(v);
      cbhl[tb + e]       = (short)h;
      cbhl[tb + e + 512] = (short)f2bf_rw(v - bf2f_rw(h));
      s += v*v;
    }
    cbn[j] = s;
    atomicMax((int*)cmaxp, __float_as_int(sqrtf(s)));  // positive floats: int-bit monotone
  }
}

// ---------------- gemm2 (r11, verified): 32px x 64out tiles ----------------
template<int KCH, int INMODE, bool OUTSILU, bool ATOMIC, int LEVELS>
__global__ __launch_bounds__(256) void gemm2_rw(
    const float* __restrict__ inF, const float* __restrict__ inF2,
    const void* __restrict__ inV,
    const void* __restrict__ W, const void* __restrict__ biasO,
    const void* __restrict__ sbA, const void* __restrict__ sbB,
    const int* __restrict__ idxin, const float* __restrict__ cb32,
    float* __restrict__ outF, const float* __restrict__ flags,
    int KDIM, int OUTC, int o_off, int b_base, int ib_sub, int ob_sub)
{
  __shared__ float As[32][32];
  __shared__ float Bs[32][68];
  __shared__ int   IdxS[32][32];

  const int f32m = (flags[0] != 0.f);
  const int t  = threadIdx.x;
  const int q0 = (blockIdx.x << 5) + (b_base << 8);
  const int b  = q0 >> 8;
  const int p0 = q0 & 255;
  const int o0 = blockIdx.y << 6;
  const int k0base = blockIdx.z * KCH;
  const int tx = t & 15, ty = t >> 4;
  float acc[4][2] = {};

  const int sch = t >> 3, spx = (t & 7) << 2;

  if constexpr (INMODE == 3){
    #pragma unroll
    for (int j = 0; j < 4; ++j){
      const int p = p0 + spx + j;
      if constexpr (LEVELS == 4){
        const int l = sch >> 3, kp = sch & 7;
        IdxS[sch][spx + j] = idxin[b*8192 + (((kp << 8) + p) << 2) + l];
      } else {
        IdxS[sch][spx + j] = idxin[b*8192 + (sch << 8) + p];
      }
    }
    __syncthreads();
  }

  for (int kc = 0; kc < KCH; kc += 32){
    const int k0 = k0base + kc;
    if constexpr (INMODE == 0){
      const float4 v = *reinterpret_cast<const float4*>(
          &inF[(((b - ib_sub)*KDIM + k0 + sch) << 8) + p0 + spx]);
      *reinterpret_cast<float4*>(&As[sch][spx]) = v;
    } else if constexpr (INMODE == 2){
      if (f32m){
        const float* xf = (const float*)inV;
        float4 v = *reinterpret_cast<const float4*>(&xf[((b*KDIM + k0 + sch) << 8) + p0 + spx]);
        v.x = silu_rw(v.x); v.y = silu_rw(v.y); v.z = silu_rw(v.z); v.w = silu_rw(v.w);
        *reinterpret_cast<float4*>(&As[sch][spx]) = v;
      } else {
        const __hip_bfloat16* xb = (const __hip_bfloat16*)inV;
        const int off = ((b*KDIM + k0 + sch) << 8) + p0 + spx;
        #pragma unroll
        for (int j = 0; j < 4; ++j) As[sch][spx + j] = silu_rw(b2f_rw(xb[off + j]));
      }
    } else if constexpr (INMODE == 3){
      const int e = k0 >> 5;
      #pragma unroll
      for (int j = 0; j < 4; ++j)
        As[sch][spx + j] = cb32[((IdxS[sch][spx + j] & 1023) << 5) + e];
    } else { // INMODE 5
      const float* src = (k0 < 128) ? inF : inF2;
      const void* sb   = (k0 < 128) ? sbA : sbB;
      const int kh = k0 & 127;
      const float bb = ldv_rw(sb, kh + sch, f32m);
      float4 v = *reinterpret_cast<const float4*>(&src[((b*128 + kh + sch) << 8) + p0 + spx]);
      v.x = silu_rw(v.x + bb); v.y = silu_rw(v.y + bb);
      v.z = silu_rw(v.z + bb); v.w = silu_rw(v.w + bb);
      *reinterpret_cast<float4*>(&As[sch][spx]) = v;
    }
    if (f32m){
      const float* Wf = (const float*)W;
      #pragma unroll
      for (int r = 0; r < 8; ++r){
        int ii = t + (r << 8); int oo = ii >> 5, cc = ii & 31;
        Bs[cc][oo] = Wf[(o0 + oo)*KDIM + k0 + cc];
      }
    } else {
      const __hip_bfloat16* Wb = (const __hip_bfloat16*)W;
      #pragma unroll
      for (int r = 0; r < 8; ++r){
        int ii = t + (r << 8); int oo = ii >> 5, cc = ii & 31;
        Bs[cc][oo] = b2f_rw(Wb[(o0 + oo)*KDIM + k0 + cc]);
      }
    }
    __syncthreads();
    #pragma unroll
    for (int kk = 0; kk < 32; ++kk){
      const float2 a = *reinterpret_cast<const float2*>(&As[kk][tx << 1]);
      const float4 w = *reinterpret_cast<const float4*>(&Bs[kk][ty << 2]);
      acc[0][0] += w.x*a.x; acc[0][1] += w.x*a.y;
      acc[1][0] += w.y*a.x; acc[1][1] += w.y*a.y;
      acc[2][0] += w.z*a.x; acc[2][1] += w.z*a.y;
      acc[3][0] += w.w*a.x; acc[3][1] += w.w*a.y;
    }
    __syncthreads();
  }
  #pragma unroll
  for (int i = 0; i < 4; ++i){
    const int o = o0 + (ty << 2) + i;
    const int base = (((b - ob_sub)*OUTC + o_off + o) << 8) + p0 + (tx << 1);
    if constexpr (ATOMIC){
      atomicAdd(&outF[base + 0], acc[i][0]);
      atomicAdd(&outF[base + 1], acc[i][1]);
    } else {
      const float bb = ldv_rw(biasO, o, f32m);
      float v0 = acc[i][0] + bb, v1 = acc[i][1] + bb;
      if constexpr (OUTSILU){ v0 = silu_rw(v0); v1 = silu_rw(v1); }
      *reinterpret_cast<float2*>(&outF[base]) = make_float2(v0, v1);
    }
  }
}

// ---------------- per-sample LN stats over silu(h_half) ----------------
__global__ __launch_bounds__(256) void stats_rw(const float* __restrict__ h, float* __restrict__ stats){
  const int b = blockIdx.x >> 1, half = blockIdx.x & 1;
  const float* base = h + ((b*256 + half*128) << 8);
  float s = 0.f, s2 = 0.f;
  for (int i = threadIdx.x; i < 32768; i += 256){
    float a = silu_rw(base[i]);
    s += a; s2 += a*a;
  }
  __shared__ float sh[2][256];
  sh[0][threadIdx.x] = s; sh[1][threadIdx.x] = s2;
  __syncthreads();
  for (int st = 128; st > 0; st >>= 1){
    if (threadIdx.x < st){
      sh[0][threadIdx.x] += sh[0][threadIdx.x + st];
      sh[1][threadIdx.x] += sh[1][threadIdx.x + st];
    }
    __syncthreads();
  }
  if (threadIdx.x == 0){
    float mu  = sh[0][0] * (1.f/32768.f);
    float var = sh[1][0] * (1.f/32768.f) - mu*mu;
    stats[half*32 + b]      = mu;
    stats[half*32 + 16 + b] = 1.f / sqrtf(var + 1e-5f);
  }
}

// ---------------- LN apply ----------------
__global__ __launch_bounds__(256) void ln_rw(const float* __restrict__ h,
    const void* lwp, const void* lbp, const void* lwn, const void* lbn,
    const float* __restrict__ stats, const float* __restrict__ flags,
    float* __restrict__ lnp, float* __restrict__ lnn){
  const int f32m = (flags[0] != 0.f);
  int i = blockIdx.x * 256 + threadIdx.x;
  int b = i >> 16, c = (i >> 8) & 255, p = i & 255;
  float a = silu_rw(h[i]);
  if (c < 128){
    float v = (a - stats[b]) * stats[16 + b] * ldv_rw(lwp, (c << 8) + p, f32m) + ldv_rw(lbp, (c << 8) + p, f32m);
    lnp[((b*128 + c) << 8) + p] = v;
  } else {
    int cc = c - 128;
    float v = (a - stats[32 + b]) * stats[48 + b] * ldv_rw(lwn, (cc << 8) + p, f32m) + ldv_rw(lbn, (cc << 8) + p, f32m);
    lnn[((b*128 + cc) << 8) + p] = v;
  }
}

// ---------------- VQ search v6b: 8-wave MFMA + prefetch + LDS merge --------
// Identical to r16 except launch_bounds(512,4): VGPR cap 128 (no spill).
// Block: 512 thr = 8 waves. Wave w: pixel group (w&3), code half (w>>2)
// (32 tiles of 16 codes). Per wave: 2 A-frags (32 px), prefetched B-frags
// from interleaved cbhl (hi +0 / lo +512 shorts per 2KB tile), C init =
// cn[col] -> D = cn - 2 z.c. Top-2 via fmed3; 16-lane shfl merge; cross-
// wave merge via LDS (strict < keeps lower-half j == np first-argmin).
// Cert eb = 3e-4*sqrt(zn)*cmax + 2e-6*zn, else np-bit-exact fallback.
template<int LEVELS>
__global__ __launch_bounds__(512, 4) void quantm_rw(
    const float* __restrict__ z, const short* __restrict__ cbhl,
    const float* __restrict__ cbn, const float* __restrict__ cmaxp,
    int* __restrict__ idxout, float* __restrict__ lossacc,
    int* __restrict__ cnt, int* __restrict__ list, int b_base)
{
  __shared__ float mgm1[4][4][8], mgm2[4][4][8];
  __shared__ int   mgj [4][4][8];
  __shared__ float red[4];

  const int tid  = threadIdx.x;
  const int lane = tid & 63, wid = tid >> 6;
  const int lc = lane & 15, gq = lane >> 4;
  const int pg = wid & 3, ch = wid >> 2;    // pixel group, code half
  const int bid  = blockIdx.x;
  const int bl   = bid >> 6;                // local batch
  const int rest = bid & 63;
  const int g = rest >> 1, half = rest & 1;
  int cb, wbase, wstep;
  if (LEVELS == 4){ cb = (g & 3)*8 + (g >> 2); wbase = (g >> 2)*1024 + (g & 3); wstep = 4; }
  else            { cb = g;                    wbase = g << 8;                  wstep = 1; }
  const int pb = half*128 + pg*32;

  // ---- load z rows, build -2z hi/lo bf16 A-fragments, partial |z|^2 ----
  bf16x8 ah0, al0, ah1, al1;
  float zn0 = 0.f, zn1 = 0.f;
  const int zoff = (((bl << 10) + cb) << 8) + pb + lc;
  const int e0 = gq << 3;
  #pragma unroll
  for (int i = 0; i < 8; ++i){
    const int zo = zoff + ((e0 + i) << 13);
    const float z0 = z[zo];
    const float z1 = z[zo + 16];
    zn0 += z0*z0; zn1 += z1*z1;
    const float s0 = -2.f*z0, s1 = -2.f*z1;
    const unsigned short h0 = f2bf_rw(s0);
    const unsigned short h1 = f2bf_rw(s1);
    ah0[i] = (short)h0; al0[i] = (short)f2bf_rw(s0 - bf2f_rw(h0));
    ah1[i] = (short)h1; al1[i] = (short)f2bf_rw(s1 - bf2f_rw(h1));
  }
  zn0 += __shfl_xor(zn0, 16); zn0 += __shfl_xor(zn0, 32);   // full zn for row lc
  zn1 += __shfl_xor(zn1, 16); zn1 += __shfl_xor(zn1, 32);

  float m1[8], m2[8]; int j1[8];
  #pragma unroll
  for (int s = 0; s < 8; ++s){ m1[s] = __builtin_inff(); m2[s] = __builtin_inff(); j1[s] = 0; }

  // interleaved table: wave's tiles T = ch*32 + t; shorts base:
  const short* bp  = cbhl + (ch << 15) + (lc << 5) + (gq << 3);
  const float* cnp = cbn + (ch << 9) + lc;

  bf16x8 bh  = *reinterpret_cast<const bf16x8*>(bp);
  bf16x8 blo = *reinterpret_cast<const bf16x8*>(bp + 512);
  float  cnv = cnp[0];

  #pragma unroll 2
  for (int t = 0; t < 32; ++t){
    const int tn = (t < 31) ? t + 1 : 31;      // clamped prefetch index
    const bf16x8 bhn  = *reinterpret_cast<const bf16x8*>(bp + (tn << 10));
    const bf16x8 blon = *reinterpret_cast<const bf16x8*>(bp + (tn << 10) + 512);
    const float  cnn  = cnp[tn << 4];

    f32x4 a0 = {cnv, cnv, cnv, cnv};
    f32x4 a1 = {cnv, cnv, cnv, cnv};
    a0 = __builtin_amdgcn_mfma_f32_16x16x32_bf16(ah0, bh,  a0, 0, 0, 0);
    a0 = __builtin_amdgcn_mfma_f32_16x16x32_bf16(ah0, blo, a0, 0, 0, 0);
    a0 = __builtin_amdgcn_mfma_f32_16x16x32_bf16(al0, bh,  a0, 0, 0, 0);
    a1 = __builtin_amdgcn_mfma_f32_16x16x32_bf16(ah1, bh,  a1, 0, 0, 0);
    a1 = __builtin_amdgcn_mfma_f32_16x16x32_bf16(ah1, blo, a1, 0, 0, 0);
    a1 = __builtin_amdgcn_mfma_f32_16x16x32_bf16(al1, bh,  a1, 0, 0, 0);

    const int jc = (((ch << 5) + t) << 4) + lc;
    #pragma unroll
    for (int r = 0; r < 4; ++r){
      const float d0 = a0[r];
      m2[r] = __builtin_amdgcn_fmed3f(d0, m1[r], m2[r]);
      const bool t0 = d0 < m1[r];
      j1[r] = t0 ? jc : j1[r]; m1[r] = t0 ? d0 : m1[r];
      const float d1 = a1[r];
      m2[4+r] = __builtin_amdgcn_fmed3f(d1, m1[4+r], m2[4+r]);
      const bool t1 = d1 < m1[4+r];
      j1[4+r] = t1 ? jc : j1[4+r]; m1[4+r] = t1 ? d1 : m1[4+r];
    }
    bh = bhn; blo = blon; cnv = cnn;
  }

  // ---- 16-lane top-2 merge (cols of each row live in one 16-lane group) ----
  #pragma unroll
  for (int k = 1; k < 16; k <<= 1){
    #pragma unroll
    for (int s = 0; s < 8; ++s){
      const float om1 = __shfl_xor(m1[s], k);
      const float om2 = __shfl_xor(m2[s], k);
      const int   oj  = __shfl_xor(j1[s], k);
      m2[s] = fminf(fminf(m2[s], om2), fmaxf(m1[s], om1));
      const bool tk = (om1 < m1[s]) || (om1 == m1[s] && oj < j1[s]);
      m1[s] = tk ? om1 : m1[s];
      j1[s] = tk ? oj  : j1[s];
    }
  }

  // ---- cross-wave merge: upper code-half -> LDS, lower merges ----
  if (wid >= 4 && lc == 0){
    #pragma unroll
    for (int s = 0; s < 8; ++s){
      mgm1[wid-4][gq][s] = m1[s];
      mgm2[wid-4][gq][s] = m2[s];
      mgj [wid-4][gq][s] = j1[s];
    }
  }
  __syncthreads();
  if (wid < 4){
    #pragma unroll
    for (int s = 0; s < 8; ++s){
      const float om1 = mgm1[wid][gq][s];
      const float om2 = mgm2[wid][gq][s];
      const int   oj  = mgj [wid][gq][s];
      m2[s] = fminf(fminf(m2[s], om2), fmaxf(m1[s], om1));
      const bool tk = om1 < m1[s];       // tie keeps lower half (smaller j)
      m1[s] = tk ? om1 : m1[s];
      j1[s] = tk ? oj  : j1[s];
    }

    // ---- finalize: cert test, idx write, loss, uncertain list ----
    const float cmax = cmaxp[0];
    float lossw = 0.f;
    #pragma unroll
    for (int f = 0; f < 2; ++f){
      #pragma unroll
      for (int r = 0; r < 4; ++r){
        const int s = f*4 + r;
        const int vrow = (gq << 2) + r;
        const float znv = __shfl(f == 0 ? zn0 : zn1, vrow);
        if (lc == 0){
          const int p  = pb + f*16 + vrow;
          const int gi = (b_base + bl)*8192 + wbase + p*wstep;
          idxout[gi] = j1[s];                    // provisional if uncertain
          const float eb = fmaf(2.0e-6f, znv, 3.0e-4f * sqrtf(znv) * cmax);
          if (m2[s] - m1[s] > eb){
            lossw += znv + m1[s];
          } else {
            const int pos = atomicAdd(cnt, 1);
            if (pos < 131072) list[pos] = (((bl << 5) | g) << 8) | p;
          }
        }
      }
    }
    lossw += __shfl_xor(lossw, 16);
    lossw += __shfl_xor(lossw, 32);
    if (lane == 0) red[wid] = lossw;
  }
  __syncthreads();
  if (tid == 0) atomicAdd(lossacc, red[0] + red[1] + red[2] + red[3]);
}

// ---------------- np-bit-exact f32 fallback for uncertain vectors ----------
// Replicates the reference rounding exactly: dot via ascending sequential
// fmaf (matches BLAS k-ascending FMA, r12-proven), zn via ascending
// sequential fmaf, d = (zn - 2*dot) + cn, first-min == lexicographic (d,j).
template<int LEVELS>
__global__ __launch_bounds__(256) void fb_rw(
    const float* __restrict__ z, const float* __restrict__ cb32,
    const float* __restrict__ cbn, const int* __restrict__ cnt,
    const int* __restrict__ list, int* __restrict__ idxout,
    float* __restrict__ lossacc, int b_base)
{
  const int lane = threadIdx.x & 63;
  const int wv = (blockIdx.x << 2) | (threadIdx.x >> 6);
  int n = cnt[0];
  if (n > 131072) n = 131072;
  for (int it = wv; it < n; it += 256){
    const int id = list[it];
    const int p = id & 255, g = (id >> 8) & 31, bl = id >> 13;
    int cb, w;
    if (LEVELS == 4){ cb = (g & 3)*8 + (g >> 2); w = (g >> 2)*1024 + (p << 2) + (g & 3); }
    else            { cb = g;                    w = (g << 8) + p; }
    const int zoff = (((bl << 10) + cb) << 8) + p;
    float myz = 0.f;
    if (lane < 32) myz = z[zoff + (lane << 13)];
    // zn: sequential ascending fmaf (matches np's accumulation order)
    float zn = 0.f;
    #pragma unroll
    for (int e = 0; e < 32; ++e){
      const float v = __shfl(myz, e);
      zn = fmaf(v, v, zn);
    }
    float bd = __builtin_inff(); int bj = 0;
    for (int j = lane; j < 1024; j += 64){
      const float* c = cb32 + (j << 5);
      float dot = 0.f;
      #pragma unroll
      for (int e = 0; e < 32; ++e) dot = fmaf(__shfl(myz, e), c[e], dot);
      const float d = (zn - 2.f*dot) + cbn[j];   // np's exact formula/rounding
      if (d < bd){ bd = d; bj = j; }
    }
    #pragma unroll
    for (int k = 1; k < 64; k <<= 1){
      const float od = __shfl_xor(bd, k);
      const int   oj = __shfl_xor(bj, k);
      if (od < bd || (od == bd && oj < bj)){ bd = od; bj = oj; }
    }
    if (lane == 0){
      idxout[(b_base + bl)*8192 + w] = bj;
      atomicAdd(lossacc, bd);                    // bd == |z-c|^2 (includes zn)
    }
  }
}

// ---------------- zq_p output (f32) ----------------
__global__ __launch_bounds__(256) void zqout_rw(const int* __restrict__ idxp,
    const float* __restrict__ cb32, float* __restrict__ out){
  int t = blockIdx.x * 256 + threadIdx.x;
  int l = t & 3, n = (t >> 2) & 2047, e = (t >> 13) & 31, b = t >> 18;
  int id = idxp[b*8192 + (n << 2) + l];
  out[t] = cb32[((id & 1023) << 5) + e];
}

// ---------------- zero hcat accum ----------------
__global__ __launch_bounds__(256) void zero_rw(float* __restrict__ p){
  p[blockIdx.x * 256 + threadIdx.x] = 0.f;
}

// ---------------- loss finalize ----------------
__global__ void loss_rw(const float* __restrict__ lossacc, float* __restrict__ out){
  if (threadIdx.x == 0 && blockIdx.x == 0)
    out[0] = 1.25f * (lossacc[0] + lossacc[1]) * (1.f/4194304.f);
}

extern "C" void kernel_launch(void* const* d_in, const int* in_sizes, int n_in,
                              void* d_out, int out_size, void* d_ws, size_t ws_size,
                              hipStream_t stream){
  (void)in_sizes; (void)n_in; (void)out_size;
  const void* x   = d_in[0];
  const void* ciw = d_in[1];
  const void* cib = d_in[2];
  const void* lwp = d_in[3];
  const void* lbp = d_in[4];
  const void* wpi = d_in[5];
  const void* bpi = d_in[6];
  const void* wpo = d_in[7];
  const void* bpo = d_in[8];
  const void* lwn = d_in[9];
  const void* lbn = d_in[10];
  const void* wni = d_in[11];
  const void* bni = d_in[12];
  const void* wno = d_in[13];
  const void* bno = d_in[14];
  const void* cbk = d_in[15];
  const void* cow = d_in[16];
  const void* cob = d_in[17];

  float* ws    = (float*)d_ws;
  float* flags = ws + FLAGS_OFF;
  float* loss  = ws + LOSS_OFF;
  float* stats = ws + STATS_OFF;
  float* cmaxp = ws + CMAX_OFF;
  float* cb32  = ws + CB32_OFF;
  float* cbn   = ws + CBN_OFF;
  int*   cnts  = (int*)(ws + CNT_OFF);
  int*   idxp  = (int*)(ws + IDXP_OFF);
  int*   idxn  = (int*)(ws + IDXN_OFF);
  short* cbhl  = (short*)(ws + CBHL_OFF);
  int*   list  = (int*)(ws + LIST_OFF);
  float* R2    = ws + R2_OFF;
  float* R3    = ws + R3_OFF;
  float* R1    = ws + R1_OFF;

  float* outO = (float*)d_out;
  float* outL = outO + 1048576;
  float* outZ = outO + 1048577;

  const size_t wsf = ws_size / 4;
  int CS = 4;
  if      (wsf >= (size_t)R1_OFF + 16u*262144u) CS = 16;
  else if (wsf >= (size_t)R1_OFF +  8u*262144u) CS = 8;

  detect_rw<<<1, 256, 0, stream>>>(cbk, ws);
  cbprep_rw<<<4, 256, 0, stream>>>(cbk, flags, cb32, cbn, cbhl, cmaxp);
  // h = conv_in(silu(x)) -> R1
  gemm2_rw<256,2,false,false,0><<<dim3(128,4), 256, 0, stream>>>(
      nullptr, nullptr, x, ciw, cib, nullptr, nullptr, nullptr, nullptr,
      R1, flags, 256, 256, 0, 0, 0, 0);
  stats_rw<<<32, 256, 0, stream>>>(R1, stats);
  ln_rw<<<4096, 256, 0, stream>>>(R1, lwp, lbp, lwn, lbn, stats, flags, R2, R3);
  // phylo: z chunks (R2 -> R1), MFMA quantize + np-exact fallback
  {
    int ci = 0;
    for (int c = 0; c < 16; c += CS, ++ci){
      gemm2_rw<128,0,true,false,0><<<dim3(CS*8,16), 256, 0, stream>>>(
          R2, nullptr, nullptr, wpi, bpi, nullptr, nullptr, nullptr, nullptr,
          R1, flags, 128, 1024, 0, c, 0, c);
      quantm_rw<4><<<CS*64, 512, 0, stream>>>(R1, cbhl, cbn, cmaxp,
                                              idxp, loss + 0, cnts + ci, list, c);
      fb_rw<4><<<64, 256, 0, stream>>>(R1, cb32, cbn, cnts + ci, list,
                                       idxp, loss + 0, c);
    }
  }
  // non-phylo
  {
    int ci = 4;
    for (int c = 0; c < 16; c += CS, ++ci){
      gemm2_rw<128,0,true,false,0><<<dim3(CS*8,16), 256, 0, stream>>>(
          R3, nullptr, nullptr, wni, bni, nullptr, nullptr, nullptr, nullptr,
          R1, flags, 128, 1024, 0, c, 0, c);
      quantm_rw<1><<<CS*64, 512, 0, stream>>>(R1, cbhl, cbn, cmaxp,
                                              idxn, loss + 1, cnts + ci, list, c);
      fb_rw<1><<<64, 256, 0, stream>>>(R1, cb32, cbn, cnts + ci, list,
                                       idxn, loss + 1, c);
    }
  }
  zqout_rw<<<16384, 256, 0, stream>>>(idxp, cb32, outZ);
  // hcat accum := 0 (R2 and R3 are contiguous: 4096*256 = 1048576 floats)
  zero_rw<<<4096, 256, 0, stream>>>(R2);
  // hout_p / hout_n: fused gather + split-K x4, atomic accum
  gemm2_rw<256,3,false,true,4><<<dim3(128,2,4), 256, 0, stream>>>(
      nullptr, nullptr, nullptr, wpo, nullptr, nullptr, nullptr, idxp, cb32,
      R2, flags, 1024, 128, 0, 0, 0, 0);
  gemm2_rw<256,3,false,true,1><<<dim3(128,2,4), 256, 0, stream>>>(
      nullptr, nullptr, nullptr, wno, nullptr, nullptr, nullptr, idxn, cb32,
      R3, flags, 1024, 128, 0, 0, 0, 0);
  // out = conv_out(silu(hcat + hout_bias))
  gemm2_rw<256,5,false,false,0><<<dim3(128,4), 256, 0, stream>>>(
      R2, R3, nullptr, cow, cob, bpo, bno, nullptr, nullptr,
      outO, flags, 256, 256, 0, 0, 0, 0);
  loss_rw<<<1, 64, 0, stream>>>(loss, outL);
}

// Round 6
// 535.066 us; speedup vs baseline: 1.2772x; 1.1300x over previous
//
#include <hip/hip_runtime.h>
#include <hip/hip_bf16.h>

// Round 18: fb_rw de-serialization. r17 counters: fb_rw 68us x2 = 136us =
// new top cost (was hidden under quantm since r14); VALUBusy 1.6%, Occ
// 2.5%, HBM 0.5% -> idle GPU: 64-block grid (1 wave/CU), 512-deep serial
// fmaf chain per item (j-loop not unrolled), 512 scalar cb loads/item.
// Fix (fb only; rest identical to r17, passed 604us): grid 640, stride
// gridDim*4, unroll-4 j-loop (4 indep chains), float4 cb loads, explicit
// zb[32] shfl hoist. Per-dot fmaf order (ascending e, sequential) is
// UNCHANGED -> np-bit-exact ranking preserved.
// Outputs (f32): out[1048576] | loss[1] | zq_p[4194304].

typedef float f32x4  __attribute__((ext_vector_type(4)));
typedef short bf16x8 __attribute__((ext_vector_type(8)));

__device__ __forceinline__ float silu_rw(float x){ return x / (1.f + expf(-x)); }
__device__ __forceinline__ float b2f_rw(__hip_bfloat16 v){ return __bfloat162float(v); }
__device__ __forceinline__ float ldv_rw(const void* p, int i, int f32m){
  if (f32m) return ((const float*)p)[i];
  return b2f_rw(((const __hip_bfloat16*)p)[i]);
}
__device__ __forceinline__ unsigned short f2bf_rw(float x){   // f32 -> bf16 RNE
  unsigned u = __float_as_uint(x);
  unsigned r = ((u >> 16) & 1u) + 0x7FFFu;
  return (unsigned short)((u + r) >> 16);
}
__device__ __forceinline__ float bf2f_rw(unsigned short h){
  return __uint_as_float(((unsigned)h) << 16);
}

// ---------------- workspace layout (float offsets) ----------------
#define FLAGS_OFF 0
#define LOSS_OFF  4
#define STATS_OFF 8
#define CNT_OFF   72         // 8 ints: fallback counters per chunk
#define CMAX_OFF  80         // max_j |c_j| (f32)
#define CB32_OFF  128        // 1024x32 f32
#define CBN_OFF   32896      // 1024
#define IDXP_OFF  33984      // 131072 int
#define IDXN_OFF  165056     // 131072 int
#define CBHL_OFF  296192     // interleaved hi/lo bf16 table (32768 f32 slots)
#define LIST_OFF  328960     // 131072 int (uncertain list, reused per chunk)
#define R2_OFF    460032     // lnp -> hcat_p accum (524288)
#define R3_OFF    984320     // lnn -> hcat_n accum (524288)
#define R1_OFF    1508608    // h (1048576) / z chunks (CS*262144)

// ---------------- input dtype probe + zero accumulators ----------------
__global__ __launch_bounds__(256) void detect_rw(const void* cbv, float* wsb){
  __shared__ int bad;
  if (threadIdx.x == 0) bad = 0;
  __syncthreads();
  const unsigned short* u = (const unsigned short*)cbv;
  int local = 0;
  for (int i = threadIdx.x; i < 32768; i += 256){
    unsigned e = (u[i] >> 7) & 0xFF;
    if (e >= 126) local = 1;
  }
  if (local) bad = 1;
  __syncthreads();
  if (threadIdx.x == 0){
    wsb[FLAGS_OFF] = bad ? 1.f : 0.f;   // 1.0 => inputs are f32
    wsb[LOSS_OFF] = 0.f; wsb[LOSS_OFF + 1] = 0.f;
    int* c = (int*)(wsb + CNT_OFF);
    #pragma unroll
    for (int k = 0; k < 8; ++k) c[k] = 0;
    wsb[CMAX_OFF] = 0.f;
  }
}

// ------ codebook -> f32 + |c|^2 + interleaved bf16 hi/lo tile table ------
// Tile T = j>>4 occupies shorts [T*1024, T*1024+1024): hi of code j elem e
// at T*1024 + (j&15)*32 + e, lo at +512.
__global__ __launch_bounds__(256) void cbprep_rw(const void* cbv, const float* flags,
                                                 float* cb32, float* cbn,
                                                 short* cbhl, float* cmaxp){
  const int f32m = (flags[0] != 0.f);
  int j = blockIdx.x * 256 + threadIdx.x;
  if (j < 1024){
    float s = 0.f;
    const int tb = ((j >> 4) << 10) + ((j & 15) << 5);
    for (int e = 0; e < 32; ++e){
      float v = ldv_rw(cbv, j*32 + e, f32m);
      cb32[j*32 + e] = v;
      unsigned short h = f2bf_rw(v);
      cbhl[tb + e]       = (short)h;
      cbhl[tb + e + 512] = (short)f2bf_rw(v - bf2f_rw(h));
      s += v*v;
    }
    cbn[j] = s;
    atomicMax((int*)cmaxp, __float_as_int(sqrtf(s)));  // positive floats: int-bit monotone
  }
}

// ---------------- gemm2 (r11, verified): 32px x 64out tiles ----------------
template<int KCH, int INMODE, bool OUTSILU, bool ATOMIC, int LEVELS>
__global__ __launch_bounds__(256) void gemm2_rw(
    const float* __restrict__ inF, const float* __restrict__ inF2,
    const void* __restrict__ inV,
    const void* __restrict__ W, const void* __restrict__ biasO,
    const void* __restrict__ sbA, const void* __restrict__ sbB,
    const int* __restrict__ idxin, const float* __restrict__ cb32,
    float* __restrict__ outF, const float* __restrict__ flags,
    int KDIM, int OUTC, int o_off, int b_base, int ib_sub, int ob_sub)
{
  __shared__ float As[32][32];
  __shared__ float Bs[32][68];
  __shared__ int   IdxS[32][32];

  const int f32m = (flags[0] != 0.f);
  const int t  = threadIdx.x;
  const int q0 = (blockIdx.x << 5) + (b_base << 8);
  const int b  = q0 >> 8;
  const int p0 = q0 & 255;
  const int o0 = blockIdx.y << 6;
  const int k0base = blockIdx.z * KCH;
  const int tx = t & 15, ty = t >> 4;
  float acc[4][2] = {};

  const int sch = t >> 3, spx = (t & 7) << 2;

  if constexpr (INMODE == 3){
    #pragma unroll
    for (int j = 0; j < 4; ++j){
      const int p = p0 + spx + j;
      if constexpr (LEVELS == 4){
        const int l = sch >> 3, kp = sch & 7;
        IdxS[sch][spx + j] = idxin[b*8192 + (((kp << 8) + p) << 2) + l];
      } else {
        IdxS[sch][spx + j] = idxin[b*8192 + (sch << 8) + p];
      }
    }
    __syncthreads();
  }

  for (int kc = 0; kc < KCH; kc += 32){
    const int k0 = k0base + kc;
    if constexpr (INMODE == 0){
      const float4 v = *reinterpret_cast<const float4*>(
          &inF[(((b - ib_sub)*KDIM + k0 + sch) << 8) + p0 + spx]);
      *reinterpret_cast<float4*>(&As[sch][spx]) = v;
    } else if constexpr (INMODE == 2){
      if (f32m){
        const float* xf = (const float*)inV;
        float4 v = *reinterpret_cast<const float4*>(&xf[((b*KDIM + k0 + sch) << 8) + p0 + spx]);
        v.x = silu_rw(v.x); v.y = silu_rw(v.y); v.z = silu_rw(v.z); v.w = silu_rw(v.w);
        *reinterpret_cast<float4*>(&As[sch][spx]) = v;
      } else {
        const __hip_bfloat16* xb = (const __hip_bfloat16*)inV;
        const int off = ((b*KDIM + k0 + sch) << 8) + p0 + spx;
        #pragma unroll
        for (int j = 0; j < 4; ++j) As[sch][spx + j] = silu_rw(b2f_rw(xb[off + j]));
      }
    } else if constexpr (INMODE == 3){
      const int e = k0 >> 5;
      #pragma unroll
      for (int j = 0; j < 4; ++j)
        As[sch][spx + j] = cb32[((IdxS[sch][spx + j] & 1023) << 5) + e];
    } else { // INMODE 5
      const float* src = (k0 < 128) ? inF : inF2;
      const void* sb   = (k0 < 128) ? sbA : sbB;
      const int kh = k0 & 127;
      const float bb = ldv_rw(sb, kh + sch, f32m);
      float4 v = *reinterpret_cast<const float4*>(&src[((b*128 + kh + sch) << 8) + p0 + spx]);
      v.x = silu_rw(v.x + bb); v.y = silu_rw(v.y + bb);
      v.z = silu_rw(v.z + bb); v.w = silu_rw(v.w + bb);
      *reinterpret_cast<float4*>(&As[sch][spx]) = v;
    }
    if (f32m){
      const float* Wf = (const float*)W;
      #pragma unroll
      for (int r = 0; r < 8; ++r){
        int ii = t + (r << 8); int oo = ii >> 5, cc = ii & 31;
        Bs[cc][oo] = Wf[(o0 + oo)*KDIM + k0 + cc];
      }
    } else {
      const __hip_bfloat16* Wb = (const __hip_bfloat16*)W;
      #pragma unroll
      for (int r = 0; r < 8; ++r){
        int ii = t + (r << 8); int oo = ii >> 5, cc = ii & 31;
        Bs[cc][oo] = b2f_rw(Wb[(o0 + oo)*KDIM + k0 + cc]);
      }
    }
    __syncthreads();
    #pragma unroll
    for (int kk = 0; kk < 32; ++kk){
      const float2 a = *reinterpret_cast<const float2*>(&As[kk][tx << 1]);
      const float4 w = *reinterpret_cast<const float4*>(&Bs[kk][ty << 2]);
      acc[0][0] += w.x*a.x; acc[0][1] += w.x*a.y;
      acc[1][0] += w.y*a.x; acc[1][1] += w.y*a.y;
      acc[2][0] += w.z*a.x; acc[2][1] += w.z*a.y;
      acc[3][0] += w.w*a.x; acc[3][1] += w.w*a.y;
    }
    __syncthreads();
  }
  #pragma unroll
  for (int i = 0; i < 4; ++i){
    const int o = o0 + (ty << 2) + i;
    const int base = (((b - ob_sub)*OUTC + o_off + o) << 8) + p0 + (tx << 1);
    if constexpr (ATOMIC){
      atomicAdd(&outF[base + 0], acc[i][0]);
      atomicAdd(&outF[base + 1], acc[i][1]);
    } else {
      const float bb = ldv_rw(biasO, o, f32m);
      float v0 = acc[i][0] + bb, v1 = acc[i][1] + bb;
      if constexpr (OUTSILU){ v0 = silu_rw(v0); v1 = silu_rw(v1); }
      *reinterpret_cast<float2*>(&outF[base]) = make_float2(v0, v1);
    }
  }
}

// ---------------- per-sample LN stats over silu(h_half) ----------------
__global__ __launch_bounds__(256) void stats_rw(const float* __restrict__ h, float* __restrict__ stats){
  const int b = blockIdx.x >> 1, half = blockIdx.x & 1;
  const float* base = h + ((b*256 + half*128) << 8);
  float s = 0.f, s2 = 0.f;
  for (int i = threadIdx.x; i < 32768; i += 256){
    float a = silu_rw(base[i]);
    s += a; s2 += a*a;
  }
  __shared__ float sh[2][256];
  sh[0][threadIdx.x] = s; sh[1][threadIdx.x] = s2;
  __syncthreads();
  for (int st = 128; st > 0; st >>= 1){
    if (threadIdx.x < st){
      sh[0][threadIdx.x] += sh[0][threadIdx.x + st];
      sh[1][threadIdx.x] += sh[1][threadIdx.x + st];
    }
    __syncthreads();
  }
  if (threadIdx.x == 0){
    float mu  = sh[0][0] * (1.f/32768.f);
    float var = sh[1][0] * (1.f/32768.f) - mu*mu;
    stats[half*32 + b]      = mu;
    stats[half*32 + 16 + b] = 1.f / sqrtf(var + 1e-5f);
  }
}

// ---------------- LN apply ----------------
__global__ __launch_bounds__(256) void ln_rw(const float* __restrict__ h,
    const void* lwp, const void* lbp, const void* lwn, const void* lbn,
    const float* __restrict__ stats, const float* __restrict__ flags,
    float* __restrict__ lnp, float* __restrict__ lnn){
  const int f32m = (flags[0] != 0.f);
  int i = blockIdx.x * 256 + threadIdx.x;
  int b = i >> 16, c = (i >> 8) & 255, p = i & 255;
  float a = silu_rw(h[i]);
  if (c < 128){
    float v = (a - stats[b]) * stats[16 + b] * ldv_rw(lwp, (c << 8) + p, f32m) + ldv_rw(lbp, (c << 8) + p, f32m);
    lnp[((b*128 + c) << 8) + p] = v;
  } else {
    int cc = c - 128;
    float v = (a - stats[32 + b]) * stats[48 + b] * ldv_rw(lwn, (cc << 8) + p, f32m) + ldv_rw(lbn, (cc << 8) + p, f32m);
    lnn[((b*128 + cc) << 8) + p] = v;
  }
}

// ---------------- VQ search v6b: 8-wave MFMA + prefetch + LDS merge --------
// launch_bounds(512,4): VGPR cap 128 (no spill; r17-verified).
// Block: 512 thr = 8 waves. Wave w: pixel group (w&3), code half (w>>2)
// (32 tiles of 16 codes). Per wave: 2 A-frags (32 px), prefetched B-frags
// from interleaved cbhl (hi +0 / lo +512 shorts per 2KB tile), C init =
// cn[col] -> D = cn - 2 z.c. Top-2 via fmed3; 16-lane shfl merge; cross-
// wave merge via LDS (strict < keeps lower-half j == np first-argmin).
// Cert eb = 3e-4*sqrt(zn)*cmax + 2e-6*zn, else np-bit-exact fallback.
template<int LEVELS>
__global__ __launch_bounds__(512, 4) void quantm_rw(
    const float* __restrict__ z, const short* __restrict__ cbhl,
    const float* __restrict__ cbn, const float* __restrict__ cmaxp,
    int* __restrict__ idxout, float* __restrict__ lossacc,
    int* __restrict__ cnt, int* __restrict__ list, int b_base)
{
  __shared__ float mgm1[4][4][8], mgm2[4][4][8];
  __shared__ int   mgj [4][4][8];
  __shared__ float red[4];

  const int tid  = threadIdx.x;
  const int lane = tid & 63, wid = tid >> 6;
  const int lc = lane & 15, gq = lane >> 4;
  const int pg = wid & 3, ch = wid >> 2;    // pixel group, code half
  const int bid  = blockIdx.x;
  const int bl   = bid >> 6;                // local batch
  const int rest = bid & 63;
  const int g = rest >> 1, half = rest & 1;
  int cb, wbase, wstep;
  if (LEVELS == 4){ cb = (g & 3)*8 + (g >> 2); wbase = (g >> 2)*1024 + (g & 3); wstep = 4; }
  else            { cb = g;                    wbase = g << 8;                  wstep = 1; }
  const int pb = half*128 + pg*32;

  // ---- load z rows, build -2z hi/lo bf16 A-fragments, partial |z|^2 ----
  bf16x8 ah0, al0, ah1, al1;
  float zn0 = 0.f, zn1 = 0.f;
  const int zoff = (((bl << 10) + cb) << 8) + pb + lc;
  const int e0 = gq << 3;
  #pragma unroll
  for (int i = 0; i < 8; ++i){
    const int zo = zoff + ((e0 + i) << 13);
    const float z0 = z[zo];
    const float z1 = z[zo + 16];
    zn0 += z0*z0; zn1 += z1*z1;
    const float s0 = -2.f*z0, s1 = -2.f*z1;
    const unsigned short h0 = f2bf_rw(s0);
    const unsigned short h1 = f2bf_rw(s1);
    ah0[i] = (short)h0; al0[i] = (short)f2bf_rw(s0 - bf2f_rw(h0));
    ah1[i] = (short)h1; al1[i] = (short)f2bf_rw(s1 - bf2f_rw(h1));
  }
  zn0 += __shfl_xor(zn0, 16); zn0 += __shfl_xor(zn0, 32);   // full zn for row lc
  zn1 += __shfl_xor(zn1, 16); zn1 += __shfl_xor(zn1, 32);

  float m1[8], m2[8]; int j1[8];
  #pragma unroll
  for (int s = 0; s < 8; ++s){ m1[s] = __builtin_inff(); m2[s] = __builtin_inff(); j1[s] = 0; }

  // interleaved table: wave's tiles T = ch*32 + t; shorts base:
  const short* bp  = cbhl + (ch << 15) + (lc << 5) + (gq << 3);
  const float* cnp = cbn + (ch << 9) + lc;

  bf16x8 bh  = *reinterpret_cast<const bf16x8*>(bp);
  bf16x8 blo = *reinterpret_cast<const bf16x8*>(bp + 512);
  float  cnv = cnp[0];

  #pragma unroll 2
  for (int t = 0; t < 32; ++t){
    const int tn = (t < 31) ? t + 1 : 31;      // clamped prefetch index
    const bf16x8 bhn  = *reinterpret_cast<const bf16x8*>(bp + (tn << 10));
    const bf16x8 blon = *reinterpret_cast<const bf16x8*>(bp + (tn << 10) + 512);
    const float  cnn  = cnp[tn << 4];

    f32x4 a0 = {cnv, cnv, cnv, cnv};
    f32x4 a1 = {cnv, cnv, cnv, cnv};
    a0 = __builtin_amdgcn_mfma_f32_16x16x32_bf16(ah0, bh,  a0, 0, 0, 0);
    a0 = __builtin_amdgcn_mfma_f32_16x16x32_bf16(ah0, blo, a0, 0, 0, 0);
    a0 = __builtin_amdgcn_mfma_f32_16x16x32_bf16(al0, bh,  a0, 0, 0, 0);
    a1 = __builtin_amdgcn_mfma_f32_16x16x32_bf16(ah1, bh,  a1, 0, 0, 0);
    a1 = __builtin_amdgcn_mfma_f32_16x16x32_bf16(ah1, blo, a1, 0, 0, 0);
    a1 = __builtin_amdgcn_mfma_f32_16x16x32_bf16(al1, bh,  a1, 0, 0, 0);

    const int jc = (((ch << 5) + t) << 4) + lc;
    #pragma unroll
    for (int r = 0; r < 4; ++r){
      const float d0 = a0[r];
      m2[r] = __builtin_amdgcn_fmed3f(d0, m1[r], m2[r]);
      const bool t0 = d0 < m1[r];
      j1[r] = t0 ? jc : j1[r]; m1[r] = t0 ? d0 : m1[r];
      const float d1 = a1[r];
      m2[4+r] = __builtin_amdgcn_fmed3f(d1, m1[4+r], m2[4+r]);
      const bool t1 = d1 < m1[4+r];
      j1[4+r] = t1 ? jc : j1[4+r]; m1[4+r] = t1 ? d1 : m1[4+r];
    }
    bh = bhn; blo = blon; cnv = cnn;
  }

  // ---- 16-lane top-2 merge (cols of each row live in one 16-lane group) ----
  #pragma unroll
  for (int k = 1; k < 16; k <<= 1){
    #pragma unroll
    for (int s = 0; s < 8; ++s){
      const float om1 = __shfl_xor(m1[s], k);
      const float om2 = __shfl_xor(m2[s], k);
      const int   oj  = __shfl_xor(j1[s], k);
      m2[s] = fminf(fminf(m2[s], om2), fmaxf(m1[s], om1));
      const bool tk = (om1 < m1[s]) || (om1 == m1[s] && oj < j1[s]);
      m1[s] = tk ? om1 : m1[s];
      j1[s] = tk ? oj  : j1[s];
    }
  }

  // ---- cross-wave merge: upper code-half -> LDS, lower merges ----
  if (wid >= 4 && lc == 0){
    #pragma unroll
    for (int s = 0; s < 8; ++s){
      mgm1[wid-4][gq][s] = m1[s];
      mgm2[wid-4][gq][s] = m2[s];
      mgj [wid-4][gq][s] = j1[s];
    }
  }
  __syncthreads();
  if (wid < 4){
    #pragma unroll
    for (int s = 0; s < 8; ++s){
      const float om1 = mgm1[wid][gq][s];
      const float om2 = mgm2[wid][gq][s];
      const int   oj  = mgj [wid][gq][s];
      m2[s] = fminf(fminf(m2[s], om2), fmaxf(m1[s], om1));
      const bool tk = om1 < m1[s];       // tie keeps lower half (smaller j)
      m1[s] = tk ? om1 : m1[s];
      j1[s] = tk ? oj  : j1[s];
    }

    // ---- finalize: cert test, idx write, loss, uncertain list ----
    const float cmax = cmaxp[0];
    float lossw = 0.f;
    #pragma unroll
    for (int f = 0; f < 2; ++f){
      #pragma unroll
      for (int r = 0; r < 4; ++r){
        const int s = f*4 + r;
        const int vrow = (gq << 2) + r;
        const float znv = __shfl(f == 0 ? zn0 : zn1, vrow);
        if (lc == 0){
          const int p  = pb + f*16 + vrow;
          const int gi = (b_base + bl)*8192 + wbase + p*wstep;
          idxout[gi] = j1[s];                    // provisional if uncertain
          const float eb = fmaf(2.0e-6f, znv, 3.0e-4f * sqrtf(znv) * cmax);
          if (m2[s] - m1[s] > eb){
            lossw += znv + m1[s];
          } else {
            const int pos = atomicAdd(cnt, 1);
            if (pos < 131072) list[pos] = (((bl << 5) | g) << 8) | p;
          }
        }
      }
    }
    lossw += __shfl_xor(lossw, 16);
    lossw += __shfl_xor(lossw, 32);
    if (lane == 0) red[wid] = lossw;
  }
  __syncthreads();
  if (tid == 0) atomicAdd(lossacc, red[0] + red[1] + red[2] + red[3]);
}

// ---------------- np-bit-exact f32 fallback for uncertain vectors ----------
// Replicates the reference rounding exactly: dot via ascending sequential
// fmaf (matches BLAS k-ascending FMA, r12-proven), zn via ascending
// sequential fmaf, d = (zn - 2*dot) + cn, first-min == lexicographic (d,j).
// v2: 640-block grid, unroll-4 j-loop (4 indep chains), float4 cb loads,
// explicit zb[] broadcast hoist. Per-dot fmaf ORDER unchanged.
template<int LEVELS>
__global__ __launch_bounds__(256) void fb_rw(
    const float* __restrict__ z, const float* __restrict__ cb32,
    const float* __restrict__ cbn, const int* __restrict__ cnt,
    const int* __restrict__ list, int* __restrict__ idxout,
    float* __restrict__ lossacc, int b_base)
{
  const int lane = threadIdx.x & 63;
  const int wv = (blockIdx.x << 2) | (threadIdx.x >> 6);
  const int nw = gridDim.x << 2;
  int n = cnt[0];
  if (n > 131072) n = 131072;
  for (int it = wv; it < n; it += nw){
    const int id = list[it];
    const int p = id & 255, g = (id >> 8) & 31, bl = id >> 13;
    int cb, w;
    if (LEVELS == 4){ cb = (g & 3)*8 + (g >> 2); w = (g >> 2)*1024 + (p << 2) + (g & 3); }
    else            { cb = g;                    w = (g << 8) + p; }
    const int zoff = (((bl << 10) + cb) << 8) + p;
    float myz = 0.f;
    if (lane < 32) myz = z[zoff + (lane << 13)];
    // broadcast z to all lanes (register array; compile-time indexed)
    float zb[32];
    #pragma unroll
    for (int e = 0; e < 32; ++e) zb[e] = __shfl(myz, e);
    // zn: sequential ascending fmaf (matches np's accumulation order)
    float zn = 0.f;
    #pragma unroll
    for (int e = 0; e < 32; ++e) zn = fmaf(zb[e], zb[e], zn);
    float bd = __builtin_inff(); int bj = 0;
    #pragma unroll 4
    for (int jj = 0; jj < 16; ++jj){
      const int j = (jj << 6) + lane;
      const float4* c4 = reinterpret_cast<const float4*>(cb32 + (j << 5));
      float dot = 0.f;
      #pragma unroll
      for (int e4 = 0; e4 < 8; ++e4){
        const float4 cv = c4[e4];
        dot = fmaf(zb[(e4 << 2) + 0], cv.x, dot);
        dot = fmaf(zb[(e4 << 2) + 1], cv.y, dot);
        dot = fmaf(zb[(e4 << 2) + 2], cv.z, dot);
        dot = fmaf(zb[(e4 << 2) + 3], cv.w, dot);
      }
      const float d = (zn - 2.f*dot) + cbn[j];   // np's exact formula/rounding
      if (d < bd){ bd = d; bj = j; }
    }
    #pragma unroll
    for (int k = 1; k < 64; k <<= 1){
      const float od = __shfl_xor(bd, k);
      const int   oj = __shfl_xor(bj, k);
      if (od < bd || (od == bd && oj < bj)){ bd = od; bj = oj; }
    }
    if (lane == 0){
      idxout[(b_base + bl)*8192 + w] = bj;
      atomicAdd(lossacc, bd);                    // bd == |z-c|^2 (includes zn)
    }
  }
}

// ---------------- zq_p output (f32) ----------------
__global__ __launch_bounds__(256) void zqout_rw(const int* __restrict__ idxp,
    const float* __restrict__ cb32, float* __restrict__ out){
  int t = blockIdx.x * 256 + threadIdx.x;
  int l = t & 3, n = (t >> 2) & 2047, e = (t >> 13) & 31, b = t >> 18;
  int id = idxp[b*8192 + (n << 2) + l];
  out[t] = cb32[((id & 1023) << 5) + e];
}

// ---------------- zero hcat accum ----------------
__global__ __launch_bounds__(256) void zero_rw(float* __restrict__ p){
  p[blockIdx.x * 256 + threadIdx.x] = 0.f;
}

// ---------------- loss finalize ----------------
__global__ void loss_rw(const float* __restrict__ lossacc, float* __restrict__ out){
  if (threadIdx.x == 0 && blockIdx.x == 0)
    out[0] = 1.25f * (lossacc[0] + lossacc[1]) * (1.f/4194304.f);
}

extern "C" void kernel_launch(void* const* d_in, const int* in_sizes, int n_in,
                              void* d_out, int out_size, void* d_ws, size_t ws_size,
                              hipStream_t stream){
  (void)in_sizes; (void)n_in; (void)out_size;
  const void* x   = d_in[0];
  const void* ciw = d_in[1];
  const void* cib = d_in[2];
  const void* lwp = d_in[3];
  const void* lbp = d_in[4];
  const void* wpi = d_in[5];
  const void* bpi = d_in[6];
  const void* wpo = d_in[7];
  const void* bpo = d_in[8];
  const void* lwn = d_in[9];
  const void* lbn = d_in[10];
  const void* wni = d_in[11];
  const void* bni = d_in[12];
  const void* wno = d_in[13];
  const void* bno = d_in[14];
  const void* cbk = d_in[15];
  const void* cow = d_in[16];
  const void* cob = d_in[17];

  float* ws    = (float*)d_ws;
  float* flags = ws + FLAGS_OFF;
  float* loss  = ws + LOSS_OFF;
  float* stats = ws + STATS_OFF;
  float* cmaxp = ws + CMAX_OFF;
  float* cb32  = ws + CB32_OFF;
  float* cbn   = ws + CBN_OFF;
  int*   cnts  = (int*)(ws + CNT_OFF);
  int*   idxp  = (int*)(ws + IDXP_OFF);
  int*   idxn  = (int*)(ws + IDXN_OFF);
  short* cbhl  = (short*)(ws + CBHL_OFF);
  int*   list  = (int*)(ws + LIST_OFF);
  float* R2    = ws + R2_OFF;
  float* R3    = ws + R3_OFF;
  float* R1    = ws + R1_OFF;

  float* outO = (float*)d_out;
  float* outL = outO + 1048576;
  float* outZ = outO + 1048577;

  const size_t wsf = ws_size / 4;
  int CS = 4;
  if      (wsf >= (size_t)R1_OFF + 16u*262144u) CS = 16;
  else if (wsf >= (size_t)R1_OFF +  8u*262144u) CS = 8;

  detect_rw<<<1, 256, 0, stream>>>(cbk, ws);
  cbprep_rw<<<4, 256, 0, stream>>>(cbk, flags, cb32, cbn, cbhl, cmaxp);
  // h = conv_in(silu(x)) -> R1
  gemm2_rw<256,2,false,false,0><<<dim3(128,4), 256, 0, stream>>>(
      nullptr, nullptr, x, ciw, cib, nullptr, nullptr, nullptr, nullptr,
      R1, flags, 256, 256, 0, 0, 0, 0);
  stats_rw<<<32, 256, 0, stream>>>(R1, stats);
  ln_rw<<<4096, 256, 0, stream>>>(R1, lwp, lbp, lwn, lbn, stats, flags, R2, R3);
  // phylo: z chunks (R2 -> R1), MFMA quantize + np-exact fallback
  {
    int ci = 0;
    for (int c = 0; c < 16; c += CS, ++ci){
      gemm2_rw<128,0,true,false,0><<<dim3(CS*8,16), 256, 0, stream>>>(
          R2, nullptr, nullptr, wpi, bpi, nullptr, nullptr, nullptr, nullptr,
          R1, flags, 128, 1024, 0, c, 0, c);
      quantm_rw<4><<<CS*64, 512, 0, stream>>>(R1, cbhl, cbn, cmaxp,
                                              idxp, loss + 0, cnts + ci, list, c);
      fb_rw<4><<<640, 256, 0, stream>>>(R1, cb32, cbn, cnts + ci, list,
                                        idxp, loss + 0, c);
    }
  }
  // non-phylo
  {
    int ci = 4;
    for (int c = 0; c < 16; c += CS, ++ci){
      gemm2_rw<128,0,true,false,0><<<dim3(CS*8,16), 256, 0, stream>>>(
          R3, nullptr, nullptr, wni, bni, nullptr, nullptr, nullptr, nullptr,
          R1, flags, 128, 1024, 0, c, 0, c);
      quantm_rw<1><<<CS*64, 512, 0, stream>>>(R1, cbhl, cbn, cmaxp,
                                              idxn, loss + 1, cnts + ci, list, c);
      fb_rw<1><<<640, 256, 0, stream>>>(R1, cb32, cbn, cnts + ci, list,
                                        idxn, loss + 1, c);
    }
  }
  zqout_rw<<<16384, 256, 0, stream>>>(idxp, cb32, outZ);
  // hcat accum := 0 (R2 and R3 are contiguous: 4096*256 = 1048576 floats)
  zero_rw<<<4096, 256, 0, stream>>>(R2);
  // hout_p / hout_n: fused gather + split-K x4, atomic accum
  gemm2_rw<256,3,false,true,4><<<dim3(128,2,4), 256, 0, stream>>>(
      nullptr, nullptr, nullptr, wpo, nullptr, nullptr, nullptr, idxp, cb32,
      R2, flags, 1024, 128, 0, 0, 0, 0);
  gemm2_rw<256,3,false,true,1><<<dim3(128,2,4), 256, 0, stream>>>(
      nullptr, nullptr, nullptr, wno, nullptr, nullptr, nullptr, idxn, cb32,
      R3, flags, 1024, 128, 0, 0, 0, 0);
  // out = conv_out(silu(hcat + hout_bias))
  gemm2_rw<256,5,false,false,0><<<dim3(128,4), 256, 0, stream>>>(
      R2, R3, nullptr, cow, cob, bpo, bno, nullptr, nullptr,
      outO, flags, 256, 256, 0, 0, 0, 0);
  loss_rw<<<1, 64, 0, stream>>>(loss, outL);
}